// Round 1
// 556.117 us; speedup vs baseline: 1.1766x; 1.1766x over previous
//
#include <hip/hip_runtime.h>
#include <math.h>

// Fused attention block: QKV proj -> per-head RMSNorm -> RoPE (+q_gain) ->
// GQA causal flash attention -> output proj.  FP32 I/O, bf16 MFMA internal.
//
// Shapes: B=4 T=2048 H=16 KVH=4 HD=128 D=2048 KVD=512.
//
// R4 changes vs R3 (attn 237us, MfmaUtil 12.3%, VALUBusy 27%, occupancy 23%,
// VGPR capped at 64 by launch_bounds(256,4) -> spills):
//  - attn: double-buffered K/V LDS + software prefetch. Raw s_barrier +
//    counted "s_waitcnt vmcnt(8)" (never vmcnt(0) mid-loop) so the next
//    tile's 8 global_load_lds stay in flight across the barrier (T3/T4).
//  - attn: 128 q-rows per block (2 passes over each staged K/V tile) ->
//    staging + barriers per FLOP halved, K/V re-reads halved.
//  - attn: launch_bounds(256,2) -> 256-VGPR budget, no spills.
//    LDS 40KB -> 72KB (2 blocks/CU).
//  - attn grid: bh fastest, qt descending -> biggest blocks fill first.

typedef float f32x4 __attribute__((ext_vector_type(4)));
typedef __bf16 bf16x8 __attribute__((ext_vector_type(8)));
typedef __bf16 bf16x4 __attribute__((ext_vector_type(4)));

__device__ __forceinline__ void load_lds16(const __bf16* g, __bf16* l) {
    __builtin_amdgcn_global_load_lds(
        (const __attribute__((address_space(1))) void*)g,
        (__attribute__((address_space(3))) void*)l, 16, 0, 0);
}

// ---------------------------------------------------------------------------
// fp32 -> bf16 conversion (n divisible by 4)
// ---------------------------------------------------------------------------
__global__ __launch_bounds__(256) void cvt_f32_bf16(
    const float* __restrict__ src, __bf16* __restrict__ dst, int n)
{
    int i = (blockIdx.x * 256 + threadIdx.x) * 4;
    if (i < n) {
        float4 v = *(const float4*)(src + i);
        bf16x4 o = {(__bf16)v.x, (__bf16)v.y, (__bf16)v.z, (__bf16)v.w};
        *(bf16x4*)(dst + i) = o;
    }
}

// ---------------------------------------------------------------------------
// GEMM: C[M][N] = A[M][K] * W[N][K]^T   (row-major, bf16 in, OutT out)
// 128x128 tile, BK=32, 256 threads (4 waves, each 64x64 quadrant).
// ---------------------------------------------------------------------------
template <typename OutT>
__global__ __launch_bounds__(256) void gemm_bt(
    const __bf16* __restrict__ A, const __bf16* __restrict__ W,
    OutT* __restrict__ C, int M, int N, int K)
{
    const int bn = blockIdx.x, bm = blockIdx.y;
    const int tid = threadIdx.x;
    const int wave = tid >> 6, lane = tid & 63;
    const int quad = lane >> 4, l16 = lane & 15;

    __shared__ __bf16 As[128 * 32];
    __shared__ __bf16 Ws[128 * 32];

    const int wm = (wave & 1) * 64;
    const int wn = (wave >> 1) * 64;

    f32x4 acc[4][4] = {};

    const int srow = wave * 16 + (lane >> 2);   // + r*64
    const int scol = (lane & 3) * 8;

    const __bf16* Ag = A + (size_t)(bm * 128) * K + scol;
    const __bf16* Wg = W + (size_t)(bn * 128) * K + scol;

    for (int k0 = 0; k0 < K; k0 += 32) {
        __syncthreads();
#pragma unroll
        for (int r = 0; r < 2; ++r) {
            load_lds16(Ag + (size_t)(srow + r * 64) * K + k0, As + (r * 4 + wave) * 512);
            load_lds16(Wg + (size_t)(srow + r * 64) * K + k0, Ws + (r * 4 + wave) * 512);
        }
        __syncthreads();

        bf16x8 af[4], wf[4];
#pragma unroll
        for (int i = 0; i < 4; ++i) {
            af[i] = *(const bf16x8*)(As + (wm + i * 16 + l16) * 32 + quad * 8);
            wf[i] = *(const bf16x8*)(Ws + (wn + i * 16 + l16) * 32 + quad * 8);
        }
#pragma unroll
        for (int mi = 0; mi < 4; ++mi)
#pragma unroll
            for (int ni = 0; ni < 4; ++ni)
                acc[mi][ni] = __builtin_amdgcn_mfma_f32_16x16x32_bf16(
                    af[mi], wf[ni], acc[mi][ni], 0, 0, 0);
    }

    // epilogue: C/D layout col=l16, row=quad*4+r
#pragma unroll
    for (int mi = 0; mi < 4; ++mi) {
#pragma unroll
        for (int r = 0; r < 4; ++r) {
            int row = bm * 128 + wm + mi * 16 + quad * 4 + r;
            OutT* Cp = C + (size_t)row * N + bn * 128 + wn + l16;
#pragma unroll
            for (int ni = 0; ni < 4; ++ni)
                Cp[ni * 16] = (OutT)acc[mi][ni][r];
        }
    }
}

// ---------------------------------------------------------------------------
// Per-head RMSNorm + RoPE (+ q_gain).  One wave per 128-elem head row.
// q: [B*T][2048] (16 heads).  kv: [B*T][1024], cols 0..511 = k heads.
// ---------------------------------------------------------------------------
__global__ __launch_bounds__(256) void qk_norm_rope(
    __bf16* __restrict__ q, __bf16* __restrict__ kv,
    const float* __restrict__ q_gain)
{
    const int row = blockIdx.x * 4 + (threadIdx.x >> 6);
    const int lane = threadIdx.x & 63;
    const int BTH = 4 * 2048 * 16;

    __bf16* base;
    int t;
    float gain;
    if (row < BTH) {
        int bt = row >> 4, h = row & 15;
        base = q + (size_t)bt * 2048 + h * 128;
        t = bt & 2047;
        gain = q_gain[h];
    } else {
        int r2 = row - BTH;
        int bt = r2 >> 2, kvh = r2 & 3;
        base = kv + (size_t)bt * 1024 + kvh * 128;
        t = bt & 2047;
        gain = 1.0f;
    }

    float x0 = (float)base[lane];        // d = lane
    float x1 = (float)base[lane + 64];   // d = lane + 64

    float ss = x0 * x0 + x1 * x1;
#pragma unroll
    for (int off = 32; off; off >>= 1) ss += __shfl_xor(ss, off);
    float inv = rsqrtf(ss * (1.0f / 128.0f) + 1.1920928955078125e-07f);
    x0 *= inv; x1 *= inv;

    float freq = exp2f(-(float)lane * 0.20762050593046013f);
    float ang = (float)t * freq;
    float s, c;
    sincosf(ang, &s, &c);
    float o0 = x0 * c - x1 * s;
    float o1 = x1 * c + x0 * s;
    base[lane]      = (__bf16)(o0 * gain);
    base[lane + 64] = (__bf16)(o1 * gain);
}

// ---------------------------------------------------------------------------
// V transpose: vt[b][c][t] = kv[b][t][512 + c]   (c = kvh*128+d in [0,512))
// ---------------------------------------------------------------------------
__global__ __launch_bounds__(256) void transpose_v(
    const __bf16* __restrict__ kv, __bf16* __restrict__ vtout)
{
    __shared__ __bf16 tile[64][65];
    const int b = blockIdx.z;
    const int t0 = blockIdx.x * 64, c0 = blockIdx.y * 64;
    const __bf16* vb = kv + (size_t)b * 2048 * 1024 + 512;
    __bf16* vtb = vtout + (size_t)b * 512 * 2048;
    const int j = threadIdx.x & 63;
    const int r0 = threadIdx.x >> 6;
#pragma unroll
    for (int i = 0; i < 16; ++i) {
        int r = r0 + i * 4;
        tile[r][j] = vb[(size_t)(t0 + r) * 1024 + c0 + j];
    }
    __syncthreads();
#pragma unroll
    for (int i = 0; i < 16; ++i) {
        int r = r0 + i * 4;
        vtb[(size_t)(c0 + r) * 2048 + t0 + j] = tile[j][r];
    }
}

// ---------------------------------------------------------------------------
// Flash attention (causal, GQA).  Block = (bh, qtile128), 256 threads.
// Fixed-max softmax, XOR-swizzled LDS, Q in regs, double-buffered K/V with
// counted-vmcnt prefetch (loads stay in flight across raw s_barriers).
// Each block: 128 q-rows = 2 passes over each staged 64-row K/V tile.
// ---------------------------------------------------------------------------
__global__ __launch_bounds__(256, 2) void attn(
    const __bf16* __restrict__ q, const __bf16* __restrict__ kv,
    const __bf16* __restrict__ vt, __bf16* __restrict__ y,
    const float* __restrict__ q_gain)
{
    const int qt = 15 - blockIdx.y;  // big blocks launch first
    const int bh = blockIdx.x;
    const int b = bh >> 4, h = bh & 15, kvh = h >> 2;
    const int tid = threadIdx.x;
    const int wave = tid >> 6, lane = tid & 63;
    const int quad = lane >> 4, l16 = lane & 15;

    __shared__ __bf16 Ks[2][64 * 128];    // [kv_row][d]  chunk c at c^(row&15)
    __shared__ __bf16 Vts[2][128 * 64];   // [d][kv_row]  chunk c at c^(row&7)
    __shared__ __bf16 Ps[4 * 16 * 64];    // per-wave [qrow][kv] chunk c^(row&7)

    const int qt0 = qt * 128;
    const int wq = wave * 16;   // this wave's 16 q-rows within a 64-row pass

    // Q fragments straight from global (A-layout: 8 contiguous bf16 / lane)
    bf16x8 qf[2][4];
#pragma unroll
    for (int p = 0; p < 2; ++p) {
        const size_t qrow =
            ((size_t)b * 2048 + qt0 + p * 64 + wq + l16) * 2048 + h * 128;
#pragma unroll
        for (int t = 0; t < 4; ++t)
            qf[p][t] = *(const bf16x8*)(q + qrow + t * 32 + quad * 8);
    }

    f32x4 oacc[2][8] = {};
    float lsum[2][4] = {};

    const float sm_scale = 0.12754635f;          // 1/sqrt(128) * log2(e)
    const float mfix = 11.5f * fabsf(q_gain[h]); // >= max possible score

    const size_t kbase = (size_t)b * 2048 * 1024 + kvh * 128;      // stride 1024
    const size_t vtbase = (size_t)(b * 4 + kvh) * 128 * 2048;      // stride 2048

    const int rowK = lane >> 4, pcK = lane & 15;
    const int rowV = lane >> 3, pcV = lane & 7;

    const int nj = 2 * qt + 2;   // 64-wide kv tiles covering [0, qt0+128)

    // prologue: stage tile 0 into buf 0 (8 loads/wave)
    {
#pragma unroll
        for (int r = 0; r < 4; ++r) {
            int rrK = (r * 4 + wave) * 4 + rowK;
            int cK = pcK ^ (rrK & 15);
            load_lds16(kv + kbase + (size_t)rrK * 1024 + cK * 8,
                       &Ks[0][(r * 4 + wave) * 512]);
            int rrV = (r * 4 + wave) * 8 + rowV;
            int cV = pcV ^ (rrV & 7);
            load_lds16(vt + vtbase + (size_t)rrV * 2048 + cV * 8,
                       &Vts[0][(r * 4 + wave) * 512]);
        }
    }

    for (int jt = 0; jt < nj; ++jt) {
        const int cur = jt & 1;

        // all waves done reading buf[cur^1] -> safe to overwrite it
        asm volatile("" ::: "memory");
        __builtin_amdgcn_s_barrier();
        asm volatile("" ::: "memory");

        if (jt + 1 < nj) {
            const int j0n = (jt + 1) * 64;
#pragma unroll
            for (int r = 0; r < 4; ++r) {
                int rrK = (r * 4 + wave) * 4 + rowK;
                int cK = pcK ^ (rrK & 15);
                load_lds16(kv + kbase + (size_t)(j0n + rrK) * 1024 + cK * 8,
                           &Ks[cur ^ 1][(r * 4 + wave) * 512]);
                int rrV = (r * 4 + wave) * 8 + rowV;
                int cV = pcV ^ (rrV & 7);
                load_lds16(vt + vtbase + (size_t)rrV * 2048 + j0n + cV * 8,
                           &Vts[cur ^ 1][(r * 4 + wave) * 512]);
            }
            // wait only for the PREVIOUS stage's 8 loads (buf[cur]); the 8
            // just-issued prefetch loads stay in flight across the barrier.
            asm volatile("s_waitcnt vmcnt(8)" ::: "memory");
        } else {
            asm volatile("s_waitcnt vmcnt(0)" ::: "memory");
        }

        asm volatile("" ::: "memory");
        __builtin_amdgcn_s_barrier();   // buf[cur] fully populated for all waves
        asm volatile("" ::: "memory");

        const __bf16* Kc = Ks[cur];
        const __bf16* Vc = Vts[cur];

#pragma unroll
        for (int p = 0; p < 2; ++p) {
            const int dlim = 2 * qt + p;   // diagonal tile index for this pass
            if (jt > dlim) continue;       // only pass 0 at jt == nj-1

            // S strip (16 q-rows x 64 kv-cols) for this wave
            f32x4 sacc[4] = {};
#pragma unroll
            for (int nt = 0; nt < 4; ++nt)
#pragma unroll
                for (int t = 0; t < 4; ++t) {
                    bf16x8 kf = *(const bf16x8*)(
                        Kc + (nt * 16 + l16) * 128 + ((t * 4 + quad) ^ l16) * 8);
                    sacc[nt] = __builtin_amdgcn_mfma_f32_16x16x32_bf16(
                        qf[p][t], kf, sacc[nt], 0, 0, 0);
                }

            if (jt == dlim) {  // diagonal tile: causal mask
#pragma unroll
                for (int nt = 0; nt < 4; ++nt) {
                    int kg = nt * 16 + l16;
#pragma unroll
                    for (int r = 0; r < 4; ++r)
                        if (kg > wq + quad * 4 + r) sacc[nt][r] = -3.0e38f;
                }
            }

            // fixed-max exp; per-lane partial row sums (reduced once at end)
            float pv4[4][4];
#pragma unroll
            for (int nt = 0; nt < 4; ++nt)
#pragma unroll
                for (int r = 0; r < 4; ++r) {
                    float pv = exp2f((sacc[nt][r] - mfix) * sm_scale);
                    pv4[nt][r] = pv;
                    lsum[p][r] += pv;
                }

            // P: C-layout -> LDS (swizzled) -> A-layout (per-wave, no barrier)
            __bf16* Pw = Ps + wave * 1024;
#pragma unroll
            for (int nt = 0; nt < 4; ++nt)
#pragma unroll
                for (int r = 0; r < 4; ++r) {
                    int row = quad * 4 + r;
                    int pc = (nt * 2 + (l16 >> 3)) ^ (row & 7);
                    Pw[row * 64 + pc * 8 + (l16 & 7)] = (__bf16)pv4[nt][r];
                }

#pragma unroll
            for (int kt = 0; kt < 2; ++kt) {
                bf16x8 pf = *(const bf16x8*)(
                    Pw + l16 * 64 + ((kt * 4 + quad) ^ (l16 & 7)) * 8);
#pragma unroll
                for (int vn = 0; vn < 8; ++vn) {
                    bf16x8 vf = *(const bf16x8*)(
                        Vc + (vn * 16 + l16) * 64 + ((kt * 4 + quad) ^ (l16 & 7)) * 8);
                    oacc[p][vn] = __builtin_amdgcn_mfma_f32_16x16x32_bf16(
                        pf, vf, oacc[p][vn], 0, 0, 0);
                }
            }
        }
    }

    // final l reduction across the 16 lanes holding each row + epilogue
#pragma unroll
    for (int p = 0; p < 2; ++p) {
#pragma unroll
        for (int r = 0; r < 4; ++r)
#pragma unroll
            for (int off = 8; off; off >>= 1)
                lsum[p][r] += __shfl_xor(lsum[p][r], off);

        const size_t ybase =
            ((size_t)b * 2048 + qt0 + p * 64 + wq) * 2048 + h * 128;
#pragma unroll
        for (int r = 0; r < 4; ++r) {
            float inv = 1.0f / lsum[p][r];
            __bf16* yp = y + ybase + (size_t)(quad * 4 + r) * 2048 + l16;
#pragma unroll
            for (int vn = 0; vn < 8; ++vn)
                yp[vn * 16] = (__bf16)(oacc[p][vn][r] * inv);
        }
    }
}

// ---------------------------------------------------------------------------
extern "C" void kernel_launch(void* const* d_in, const int* in_sizes, int n_in,
                              void* d_out, int out_size, void* d_ws, size_t ws_size,
                              hipStream_t stream) {
    const float* x     = (const float*)d_in[0];
    const float* Wq    = (const float*)d_in[1];
    const float* Wk    = (const float*)d_in[2];
    const float* Wv    = (const float*)d_in[3];
    const float* Wproj = (const float*)d_in[4];
    const float* qgain = (const float*)d_in[5];
    float* outp = (float*)d_out;

    // workspace layout (bf16 elems)
    __bf16* xb  = (__bf16*)d_ws;          // 16777216
    __bf16* Wqb = xb  + 16777216;         // 4194304
    __bf16* Wkb = Wqb + 4194304;          // 1048576  (Wkb+Wvb = fused [1024][2048])
    __bf16* Wvb = Wkb + 1048576;          // 1048576
    __bf16* Wpb = Wvb + 1048576;          // 4194304
    __bf16* q   = Wpb + 4194304;          // 16777216
    __bf16* kvb = q   + 16777216;         // 8388608  [4*2048][1024]: k|v fused
    __bf16* vt  = kvb + 8388608;          // 4194304  [4][512][2048]
    __bf16* y   = q;                      // alias: 1:1 tile correspondence, safe

    dim3 blk(256);
    cvt_f32_bf16<<<dim3(16777216 / 1024), blk, 0, stream>>>(x, xb, 16777216);
    cvt_f32_bf16<<<dim3(4194304 / 1024), blk, 0, stream>>>(Wq, Wqb, 4194304);
    cvt_f32_bf16<<<dim3(1048576 / 1024), blk, 0, stream>>>(Wk, Wkb, 1048576);
    cvt_f32_bf16<<<dim3(1048576 / 1024), blk, 0, stream>>>(Wv, Wvb, 1048576);
    cvt_f32_bf16<<<dim3(4194304 / 1024), blk, 0, stream>>>(Wproj, Wpb, 4194304);

    gemm_bt<__bf16><<<dim3(16, 64), blk, 0, stream>>>(xb, Wqb, q, 8192, 2048, 2048);
    gemm_bt<__bf16><<<dim3(8, 64), blk, 0, stream>>>(xb, Wkb, kvb, 8192, 1024, 2048);
    qk_norm_rope<<<dim3((4 * 2048 * (16 + 4)) / 4), blk, 0, stream>>>(q, kvb, qgain);
    transpose_v<<<dim3(32, 8, 4), blk, 0, stream>>>(kvb, vt);
    attn<<<dim3(64, 16), blk, 0, stream>>>(q, kvb, vt, y, qgain);
    gemm_bt<float><<<dim3(16, 64), blk, 0, stream>>>(y, Wpb, outp, 8192, 2048, 2048);
}

// Round 2
// 527.598 us; speedup vs baseline: 1.2402x; 1.0541x over previous
//
#include <hip/hip_runtime.h>
#include <math.h>

// Fused attention block: QKV proj -> per-head RMSNorm -> RoPE (+q_gain) ->
// GQA causal flash attention -> output proj.  FP32 I/O, bf16 MFMA internal.
//
// Shapes: B=4 T=2048 H=16 KVH=4 HD=128 D=2048 KVD=512.
//
// R5 changes vs R4 (attn 131us; GEMMs now dominate at ~240us on the m97
// 128^2-tile 2-barrier structure, ~900TF ceiling):
//  - gemm256: 256x256 (or 256x128) tile, BK=64, 8 waves / 512 threads,
//    1 block/CU. Double-buffered LDS, counted "s_waitcnt vmcnt(8/6)" so
//    prefetch loads stay in flight across barriers (T3+T4, proven in attn).
//    Per-K-tile compute split into 4 quadrant phases, each wrapped in raw
//    s_barrier pairs + s_setprio(1) around the 16-MFMA cluster (T5).
//    LDS chunk-XOR swizzle c^(row&7) on ds_read_b128 (T2; the exact pattern
//    that measures 0 bank conflicts in attn), inverse swizzle pre-applied
//    to the global_load_lds SOURCE (linear LDS dest).
//  - All three projections use gemm256 (KV proj uses BN=128 so its grid
//    stays 256 blocks = 1/CU).

typedef float f32x4 __attribute__((ext_vector_type(4)));
typedef __bf16 bf16x8 __attribute__((ext_vector_type(8)));
typedef __bf16 bf16x4 __attribute__((ext_vector_type(4)));

__device__ __forceinline__ void load_lds16(const __bf16* g, __bf16* l) {
    __builtin_amdgcn_global_load_lds(
        (const __attribute__((address_space(1))) void*)g,
        (__attribute__((address_space(3))) void*)l, 16, 0, 0);
}

// ---------------------------------------------------------------------------
// fp32 -> bf16 conversion (n divisible by 4)
// ---------------------------------------------------------------------------
__global__ __launch_bounds__(256) void cvt_f32_bf16(
    const float* __restrict__ src, __bf16* __restrict__ dst, int n)
{
    int i = (blockIdx.x * 256 + threadIdx.x) * 4;
    if (i < n) {
        float4 v = *(const float4*)(src + i);
        bf16x4 o = {(__bf16)v.x, (__bf16)v.y, (__bf16)v.z, (__bf16)v.w};
        *(bf16x4*)(dst + i) = o;
    }
}

// ---------------------------------------------------------------------------
// GEMM: C[M][N] = A[M][K] * W[N][K]^T   (row-major, bf16 in, OutT out)
// 256x(64*NI) tile, BK=64, 512 threads (8 waves: 2 M-halves x 4 N-quarters).
// Deep pipeline: double-buffered LDS, counted vmcnt, 4 phases per K-tile.
// ---------------------------------------------------------------------------
template <int NI, typename OutT>
__global__ __launch_bounds__(512, 2) void gemm256(
    const __bf16* __restrict__ A, const __bf16* __restrict__ W,
    OutT* __restrict__ C, int M, int N, int K)
{
    constexpr int BN = 64 * NI;   // 256 (NI=4) or 128 (NI=2)
    const int bn = blockIdx.x, bm = blockIdx.y;
    const int tid = threadIdx.x;
    const int lane = tid & 63;
    const int wave = tid >> 6;
    const int quad = lane >> 4, l16 = lane & 15;
    const int wm2 = wave >> 2;    // 0..1  : M half (128 rows)
    const int wn4 = wave & 3;     // 0..3  : N quarter (16*NI cols)

    __shared__ __bf16 As[2][256 * 64];
    __shared__ __bf16 Bs[2][BN * 64];

    f32x4 acc[8][NI] = {};

    // staging geometry: each thread stages one 16B chunk per round.
    // round = 64 rows; A has 4 rounds, B has NI rounds per K-tile.
    const int sr = tid >> 3;            // 0..63 row-in-round
    const int sc = tid & 7;             // dest chunk 0..7 (linear in tid!)
    const int scs = sc ^ (sr & 7);      // pre-swizzled SOURCE chunk

    const __bf16* Ag = A + (size_t)(bm * 256 + sr) * K + scs * 8;
    const __bf16* Wg = W + (size_t)(bn * BN + sr) * K + scs * 8;
    __bf16* Asd = &As[0][0] + sr * 64 + sc * 8;
    __bf16* Bsd = &Bs[0][0] + sr * 64 + sc * 8;

    auto stage = [&](int t, int h) {
        const int k0 = t * 64;
#pragma unroll
        for (int ra = 0; ra < 4; ++ra)
            load_lds16(Ag + (size_t)(ra * 64) * K + k0,
                       Asd + h * 16384 + ra * 4096);
#pragma unroll
        for (int rb = 0; rb < NI; ++rb)
            load_lds16(Wg + (size_t)(rb * 64) * K + k0,
                       Bsd + h * (BN * 64) + rb * 4096);
    };
    auto wait_prev = [&]() {  // keep the (4+NI) just-issued loads in flight
        if constexpr (NI == 4) asm volatile("s_waitcnt vmcnt(8)" ::: "memory");
        else                   asm volatile("s_waitcnt vmcnt(6)" ::: "memory");
    };

    const int NT = K / 64;

    stage(0, 0);
    stage(1, 1);
    wait_prev();   // tile 0 (oldest 4+NI loads) landed; tile 1 in flight
    asm volatile("" ::: "memory");
    __builtin_amdgcn_s_barrier();
    asm volatile("" ::: "memory");

    for (int t = 0; t < NT; ++t) {
        const int h = t & 1;
        const __bf16* Ab = &As[h][0];
        const __bf16* Bb = &Bs[h][0];

        bf16x8 bfr[NI][2];
#pragma unroll
        for (int ph = 0; ph < 4; ++ph) {
            bf16x8 af[2][2];
#pragma unroll
            for (int j = 0; j < 2; ++j)
#pragma unroll
                for (int ks = 0; ks < 2; ++ks)
                    af[j][ks] = *(const bf16x8*)(
                        Ab + (wm2 * 128 + (ph * 2 + j) * 16 + l16) * 64 +
                        (((ks * 4 + quad) ^ (l16 & 7)) * 8));
            if (ph == 0) {
#pragma unroll
                for (int ni = 0; ni < NI; ++ni)
#pragma unroll
                    for (int ks = 0; ks < 2; ++ks)
                        bfr[ni][ks] = *(const bf16x8*)(
                            Bb + (wn4 * 16 * NI + ni * 16 + l16) * 64 +
                            (((ks * 4 + quad) ^ (l16 & 7)) * 8));
            }
            asm volatile("" ::: "memory");
            __builtin_amdgcn_s_barrier();
            asm volatile("" ::: "memory");
            __builtin_amdgcn_s_setprio(1);
#pragma unroll
            for (int j = 0; j < 2; ++j)
#pragma unroll
                for (int ni = 0; ni < NI; ++ni)
#pragma unroll
                    for (int ks = 0; ks < 2; ++ks)
                        acc[ph * 2 + j][ni] = __builtin_amdgcn_mfma_f32_16x16x32_bf16(
                            af[j][ks], bfr[ni][ks], acc[ph * 2 + j][ni], 0, 0, 0);
            __builtin_amdgcn_s_setprio(0);
            asm volatile("" ::: "memory");
            __builtin_amdgcn_s_barrier();   // buf[h] reads done after last phase
            asm volatile("" ::: "memory");
        }

        if (t + 2 < NT) {
            stage(t + 2, h);   // buf[h] freed by the phase-3 trailing barrier
            wait_prev();       // completes tile t+1's loads; t+2 stays in flight
        } else if (t + 1 < NT) {
            asm volatile("s_waitcnt vmcnt(0)" ::: "memory");
        } else {
            break;             // last tile computed; nothing outstanding
        }
        asm volatile("" ::: "memory");
        __builtin_amdgcn_s_barrier();   // buf[h^1] fully populated for all waves
        asm volatile("" ::: "memory");
    }

    // epilogue: C/D layout col=l16, row=quad*4+r
#pragma unroll
    for (int mi = 0; mi < 8; ++mi) {
#pragma unroll
        for (int r = 0; r < 4; ++r) {
            int row = bm * 256 + wm2 * 128 + mi * 16 + quad * 4 + r;
            OutT* Cp = C + (size_t)row * N + bn * BN + wn4 * 16 * NI + l16;
#pragma unroll
            for (int ni = 0; ni < NI; ++ni)
                Cp[ni * 16] = (OutT)acc[mi][ni][r];
        }
    }
}

// ---------------------------------------------------------------------------
// Per-head RMSNorm + RoPE (+ q_gain).  One wave per 128-elem head row.
// q: [B*T][2048] (16 heads).  kv: [B*T][1024], cols 0..511 = k heads.
// ---------------------------------------------------------------------------
__global__ __launch_bounds__(256) void qk_norm_rope(
    __bf16* __restrict__ q, __bf16* __restrict__ kv,
    const float* __restrict__ q_gain)
{
    const int row = blockIdx.x * 4 + (threadIdx.x >> 6);
    const int lane = threadIdx.x & 63;
    const int BTH = 4 * 2048 * 16;

    __bf16* base;
    int t;
    float gain;
    if (row < BTH) {
        int bt = row >> 4, h = row & 15;
        base = q + (size_t)bt * 2048 + h * 128;
        t = bt & 2047;
        gain = q_gain[h];
    } else {
        int r2 = row - BTH;
        int bt = r2 >> 2, kvh = r2 & 3;
        base = kv + (size_t)bt * 1024 + kvh * 128;
        t = bt & 2047;
        gain = 1.0f;
    }

    float x0 = (float)base[lane];        // d = lane
    float x1 = (float)base[lane + 64];   // d = lane + 64

    float ss = x0 * x0 + x1 * x1;
#pragma unroll
    for (int off = 32; off; off >>= 1) ss += __shfl_xor(ss, off);
    float inv = rsqrtf(ss * (1.0f / 128.0f) + 1.1920928955078125e-07f);
    x0 *= inv; x1 *= inv;

    float freq = exp2f(-(float)lane * 0.20762050593046013f);
    float ang = (float)t * freq;
    float s, c;
    sincosf(ang, &s, &c);
    float o0 = x0 * c - x1 * s;
    float o1 = x1 * c + x0 * s;
    base[lane]      = (__bf16)(o0 * gain);
    base[lane + 64] = (__bf16)(o1 * gain);
}

// ---------------------------------------------------------------------------
// V transpose: vt[b][c][t] = kv[b][t][512 + c]   (c = kvh*128+d in [0,512))
// ---------------------------------------------------------------------------
__global__ __launch_bounds__(256) void transpose_v(
    const __bf16* __restrict__ kv, __bf16* __restrict__ vtout)
{
    __shared__ __bf16 tile[64][65];
    const int b = blockIdx.z;
    const int t0 = blockIdx.x * 64, c0 = blockIdx.y * 64;
    const __bf16* vb = kv + (size_t)b * 2048 * 1024 + 512;
    __bf16* vtb = vtout + (size_t)b * 512 * 2048;
    const int j = threadIdx.x & 63;
    const int r0 = threadIdx.x >> 6;
#pragma unroll
    for (int i = 0; i < 16; ++i) {
        int r = r0 + i * 4;
        tile[r][j] = vb[(size_t)(t0 + r) * 1024 + c0 + j];
    }
    __syncthreads();
#pragma unroll
    for (int i = 0; i < 16; ++i) {
        int r = r0 + i * 4;
        vtb[(size_t)(c0 + r) * 2048 + t0 + j] = tile[j][r];
    }
}

// ---------------------------------------------------------------------------
// Flash attention (causal, GQA).  Block = (bh, qtile128), 256 threads.
// Fixed-max softmax, XOR-swizzled LDS, Q in regs, double-buffered K/V with
// counted-vmcnt prefetch (loads stay in flight across raw s_barriers).
// Each block: 128 q-rows = 2 passes over each staged 64-row K/V tile.
// ---------------------------------------------------------------------------
__global__ __launch_bounds__(256, 2) void attn(
    const __bf16* __restrict__ q, const __bf16* __restrict__ kv,
    const __bf16* __restrict__ vt, __bf16* __restrict__ y,
    const float* __restrict__ q_gain)
{
    const int qt = 15 - blockIdx.y;  // big blocks launch first
    const int bh = blockIdx.x;
    const int b = bh >> 4, h = bh & 15, kvh = h >> 2;
    const int tid = threadIdx.x;
    const int wave = tid >> 6, lane = tid & 63;
    const int quad = lane >> 4, l16 = lane & 15;

    __shared__ __bf16 Ks[2][64 * 128];    // [kv_row][d]  chunk c at c^(row&15)
    __shared__ __bf16 Vts[2][128 * 64];   // [d][kv_row]  chunk c at c^(row&7)
    __shared__ __bf16 Ps[4 * 16 * 64];    // per-wave [qrow][kv] chunk c^(row&7)

    const int qt0 = qt * 128;
    const int wq = wave * 16;   // this wave's 16 q-rows within a 64-row pass

    // Q fragments straight from global (A-layout: 8 contiguous bf16 / lane)
    bf16x8 qf[2][4];
#pragma unroll
    for (int p = 0; p < 2; ++p) {
        const size_t qrow =
            ((size_t)b * 2048 + qt0 + p * 64 + wq + l16) * 2048 + h * 128;
#pragma unroll
        for (int t = 0; t < 4; ++t)
            qf[p][t] = *(const bf16x8*)(q + qrow + t * 32 + quad * 8);
    }

    f32x4 oacc[2][8] = {};
    float lsum[2][4] = {};

    const float sm_scale = 0.12754635f;          // 1/sqrt(128) * log2(e)
    const float mfix = 11.5f * fabsf(q_gain[h]); // >= max possible score

    const size_t kbase = (size_t)b * 2048 * 1024 + kvh * 128;      // stride 1024
    const size_t vtbase = (size_t)(b * 4 + kvh) * 128 * 2048;      // stride 2048

    const int rowK = lane >> 4, pcK = lane & 15;
    const int rowV = lane >> 3, pcV = lane & 7;

    const int nj = 2 * qt + 2;   // 64-wide kv tiles covering [0, qt0+128)

    // prologue: stage tile 0 into buf 0 (8 loads/wave)
    {
#pragma unroll
        for (int r = 0; r < 4; ++r) {
            int rrK = (r * 4 + wave) * 4 + rowK;
            int cK = pcK ^ (rrK & 15);
            load_lds16(kv + kbase + (size_t)rrK * 1024 + cK * 8,
                       &Ks[0][(r * 4 + wave) * 512]);
            int rrV = (r * 4 + wave) * 8 + rowV;
            int cV = pcV ^ (rrV & 7);
            load_lds16(vt + vtbase + (size_t)rrV * 2048 + cV * 8,
                       &Vts[0][(r * 4 + wave) * 512]);
        }
    }

    for (int jt = 0; jt < nj; ++jt) {
        const int cur = jt & 1;

        // all waves done reading buf[cur^1] -> safe to overwrite it
        asm volatile("" ::: "memory");
        __builtin_amdgcn_s_barrier();
        asm volatile("" ::: "memory");

        if (jt + 1 < nj) {
            const int j0n = (jt + 1) * 64;
#pragma unroll
            for (int r = 0; r < 4; ++r) {
                int rrK = (r * 4 + wave) * 4 + rowK;
                int cK = pcK ^ (rrK & 15);
                load_lds16(kv + kbase + (size_t)(j0n + rrK) * 1024 + cK * 8,
                           &Ks[cur ^ 1][(r * 4 + wave) * 512]);
                int rrV = (r * 4 + wave) * 8 + rowV;
                int cV = pcV ^ (rrV & 7);
                load_lds16(vt + vtbase + (size_t)rrV * 2048 + j0n + cV * 8,
                           &Vts[cur ^ 1][(r * 4 + wave) * 512]);
            }
            // wait only for the PREVIOUS stage's 8 loads (buf[cur]); the 8
            // just-issued prefetch loads stay in flight across the barrier.
            asm volatile("s_waitcnt vmcnt(8)" ::: "memory");
        } else {
            asm volatile("s_waitcnt vmcnt(0)" ::: "memory");
        }

        asm volatile("" ::: "memory");
        __builtin_amdgcn_s_barrier();   // buf[cur] fully populated for all waves
        asm volatile("" ::: "memory");

        const __bf16* Kc = Ks[cur];
        const __bf16* Vc = Vts[cur];

#pragma unroll
        for (int p = 0; p < 2; ++p) {
            const int dlim = 2 * qt + p;   // diagonal tile index for this pass
            if (jt > dlim) continue;       // only pass 0 at jt == nj-1

            // S strip (16 q-rows x 64 kv-cols) for this wave
            f32x4 sacc[4] = {};
#pragma unroll
            for (int nt = 0; nt < 4; ++nt)
#pragma unroll
                for (int t = 0; t < 4; ++t) {
                    bf16x8 kf = *(const bf16x8*)(
                        Kc + (nt * 16 + l16) * 128 + ((t * 4 + quad) ^ l16) * 8);
                    sacc[nt] = __builtin_amdgcn_mfma_f32_16x16x32_bf16(
                        qf[p][t], kf, sacc[nt], 0, 0, 0);
                }

            if (jt == dlim) {  // diagonal tile: causal mask
#pragma unroll
                for (int nt = 0; nt < 4; ++nt) {
                    int kg = nt * 16 + l16;
#pragma unroll
                    for (int r = 0; r < 4; ++r)
                        if (kg > wq + quad * 4 + r) sacc[nt][r] = -3.0e38f;
                }
            }

            // fixed-max exp; per-lane partial row sums (reduced once at end)
            float pv4[4][4];
#pragma unroll
            for (int nt = 0; nt < 4; ++nt)
#pragma unroll
                for (int r = 0; r < 4; ++r) {
                    float pv = exp2f((sacc[nt][r] - mfix) * sm_scale);
                    pv4[nt][r] = pv;
                    lsum[p][r] += pv;
                }

            // P: C-layout -> LDS (swizzled) -> A-layout (per-wave, no barrier)
            __bf16* Pw = Ps + wave * 1024;
#pragma unroll
            for (int nt = 0; nt < 4; ++nt)
#pragma unroll
                for (int r = 0; r < 4; ++r) {
                    int row = quad * 4 + r;
                    int pc = (nt * 2 + (l16 >> 3)) ^ (row & 7);
                    Pw[row * 64 + pc * 8 + (l16 & 7)] = (__bf16)pv4[nt][r];
                }

#pragma unroll
            for (int kt = 0; kt < 2; ++kt) {
                bf16x8 pf = *(const bf16x8*)(
                    Pw + l16 * 64 + ((kt * 4 + quad) ^ (l16 & 7)) * 8);
#pragma unroll
                for (int vn = 0; vn < 8; ++vn) {
                    bf16x8 vf = *(const bf16x8*)(
                        Vc + (vn * 16 + l16) * 64 + ((kt * 4 + quad) ^ (l16 & 7)) * 8);
                    oacc[p][vn] = __builtin_amdgcn_mfma_f32_16x16x32_bf16(
                        pf, vf, oacc[p][vn], 0, 0, 0);
                }
            }
        }
    }

    // final l reduction across the 16 lanes holding each row + epilogue
#pragma unroll
    for (int p = 0; p < 2; ++p) {
#pragma unroll
        for (int r = 0; r < 4; ++r)
#pragma unroll
            for (int off = 8; off; off >>= 1)
                lsum[p][r] += __shfl_xor(lsum[p][r], off);

        const size_t ybase =
            ((size_t)b * 2048 + qt0 + p * 64 + wq) * 2048 + h * 128;
#pragma unroll
        for (int r = 0; r < 4; ++r) {
            float inv = 1.0f / lsum[p][r];
            __bf16* yp = y + ybase + (size_t)(quad * 4 + r) * 2048 + l16;
#pragma unroll
            for (int vn = 0; vn < 8; ++vn)
                yp[vn * 16] = (__bf16)(oacc[p][vn][r] * inv);
        }
    }
}

// ---------------------------------------------------------------------------
extern "C" void kernel_launch(void* const* d_in, const int* in_sizes, int n_in,
                              void* d_out, int out_size, void* d_ws, size_t ws_size,
                              hipStream_t stream) {
    const float* x     = (const float*)d_in[0];
    const float* Wq    = (const float*)d_in[1];
    const float* Wk    = (const float*)d_in[2];
    const float* Wv    = (const float*)d_in[3];
    const float* Wproj = (const float*)d_in[4];
    const float* qgain = (const float*)d_in[5];
    float* outp = (float*)d_out;

    // workspace layout (bf16 elems)
    __bf16* xb  = (__bf16*)d_ws;          // 16777216
    __bf16* Wqb = xb  + 16777216;         // 4194304
    __bf16* Wkb = Wqb + 4194304;          // 1048576  (Wkb+Wvb = fused [1024][2048])
    __bf16* Wvb = Wkb + 1048576;          // 1048576
    __bf16* Wpb = Wvb + 1048576;          // 4194304
    __bf16* q   = Wpb + 4194304;          // 16777216
    __bf16* kvb = q   + 16777216;         // 8388608  [4*2048][1024]: k|v fused
    __bf16* vt  = kvb + 8388608;          // 4194304  [4][512][2048]
    __bf16* y   = q;                      // alias: 1:1 tile correspondence, safe

    dim3 blk(256);
    cvt_f32_bf16<<<dim3(16777216 / 1024), blk, 0, stream>>>(x, xb, 16777216);
    cvt_f32_bf16<<<dim3(4194304 / 1024), blk, 0, stream>>>(Wq, Wqb, 4194304);
    cvt_f32_bf16<<<dim3(1048576 / 1024), blk, 0, stream>>>(Wk, Wkb, 1048576);
    cvt_f32_bf16<<<dim3(1048576 / 1024), blk, 0, stream>>>(Wv, Wvb, 1048576);
    cvt_f32_bf16<<<dim3(4194304 / 1024), blk, 0, stream>>>(Wproj, Wpb, 4194304);

    // 256-row tiles; N-tile = 256 (NI=4) or 128 (NI=2).  Grid = 256 blocks
    // = 1 block/CU for all three projections.
    gemm256<4, __bf16><<<dim3(8, 32), dim3(512), 0, stream>>>(xb, Wqb, q, 8192, 2048, 2048);
    gemm256<2, __bf16><<<dim3(8, 32), dim3(512), 0, stream>>>(xb, Wkb, kvb, 8192, 1024, 2048);
    qk_norm_rope<<<dim3((4 * 2048 * (16 + 4)) / 4), blk, 0, stream>>>(q, kvb, qgain);
    transpose_v<<<dim3(32, 8, 4), blk, 0, stream>>>(kvb, vt);
    attn<<<dim3(64, 16), blk, 0, stream>>>(q, kvb, vt, y, qgain);
    gemm256<4, float><<<dim3(8, 32), dim3(512), 0, stream>>>(y, Wpb, outp, 8192, 2048, 2048);
}

// Round 3
// 513.076 us; speedup vs baseline: 1.2753x; 1.0283x over previous
//
#include <hip/hip_runtime.h>
#include <math.h>

// Fused attention block: QKV proj -> per-head RMSNorm -> RoPE (+q_gain) ->
// GQA causal flash attention -> output proj.  FP32 I/O, bf16 MFMA internal.
//
// Shapes: B=4 T=2048 H=16 KVH=4 HD=128 D=2048 KVD=512.
//
// R6 changes vs R5 (attn 132us, MfmaUtil 22.9% == derived LDS-read ceiling:
// 68 ds_read_b128 per 64 MFMA per jt):
//  - attn: the two 64-row q-passes are FUSED so each K-frag and V-frag
//    ds_read feeds 2 MFMAs (36 reads/64 MFMA).  Both passes' P tiles live
//    in LDS at once (Ps x2, total 80KB, still 2 blocks/CU).  Causal mask
//    generalized: rel = p*64 + qrow_local - (jt-2qt)*64; the final tile's
//    pass-0 strip is fully masked (pv=0) instead of skipped.
//  - attn: s_setprio(1) around both MFMA clusters (T5).
//  - all five f32->bf16 conversions merged into one kernel (dst segments
//    are contiguous in workspace; boundaries 1024-aligned so the segment
//    branch is block-uniform).

typedef float f32x4 __attribute__((ext_vector_type(4)));
typedef __bf16 bf16x8 __attribute__((ext_vector_type(8)));
typedef __bf16 bf16x4 __attribute__((ext_vector_type(4)));

__device__ __forceinline__ void load_lds16(const __bf16* g, __bf16* l) {
    __builtin_amdgcn_global_load_lds(
        (const __attribute__((address_space(1))) void*)g,
        (__attribute__((address_space(3))) void*)l, 16, 0, 0);
}

// ---------------------------------------------------------------------------
// fp32 -> bf16 conversion of all five inputs in one launch.
// dst layout: xb | Wqb | Wkb | Wvb | Wpb  (contiguous, sizes below).
// ---------------------------------------------------------------------------
__global__ __launch_bounds__(256) void cvt_all(
    const float* __restrict__ x,  const float* __restrict__ Wq,
    const float* __restrict__ Wk, const float* __restrict__ Wv,
    const float* __restrict__ Wp, __bf16* __restrict__ dst)
{
    long long i = ((long long)blockIdx.x * 256 + threadIdx.x) * 4;
    if (i >= 27262976LL) return;
    const float* src;
    long long off;
    if (i < 16777216LL)      { src = x;  off = i; }
    else if (i < 20971520LL) { src = Wq; off = i - 16777216LL; }
    else if (i < 22020096LL) { src = Wk; off = i - 20971520LL; }
    else if (i < 23068672LL) { src = Wv; off = i - 22020096LL; }
    else                     { src = Wp; off = i - 23068672LL; }
    float4 v = *(const float4*)(src + off);
    bf16x4 o = {(__bf16)v.x, (__bf16)v.y, (__bf16)v.z, (__bf16)v.w};
    *(bf16x4*)(dst + i) = o;
}

// ---------------------------------------------------------------------------
// GEMM: C[M][N] = A[M][K] * W[N][K]^T   (row-major, bf16 in, OutT out)
// 256x(64*NI) tile, BK=64, 512 threads (8 waves: 2 M-halves x 4 N-quarters).
// Deep pipeline: double-buffered LDS, counted vmcnt, 4 phases per K-tile.
// ---------------------------------------------------------------------------
template <int NI, typename OutT>
__global__ __launch_bounds__(512, 2) void gemm256(
    const __bf16* __restrict__ A, const __bf16* __restrict__ W,
    OutT* __restrict__ C, int M, int N, int K)
{
    constexpr int BN = 64 * NI;   // 256 (NI=4) or 128 (NI=2)
    const int bn = blockIdx.x, bm = blockIdx.y;
    const int tid = threadIdx.x;
    const int lane = tid & 63;
    const int wave = tid >> 6;
    const int quad = lane >> 4, l16 = lane & 15;
    const int wm2 = wave >> 2;    // 0..1  : M half (128 rows)
    const int wn4 = wave & 3;     // 0..3  : N quarter (16*NI cols)

    __shared__ __bf16 As[2][256 * 64];
    __shared__ __bf16 Bs[2][BN * 64];

    f32x4 acc[8][NI] = {};

    // staging geometry: each thread stages one 16B chunk per round.
    // round = 64 rows; A has 4 rounds, B has NI rounds per K-tile.
    const int sr = tid >> 3;            // 0..63 row-in-round
    const int sc = tid & 7;             // dest chunk 0..7 (linear in tid!)
    const int scs = sc ^ (sr & 7);      // pre-swizzled SOURCE chunk

    const __bf16* Ag = A + (size_t)(bm * 256 + sr) * K + scs * 8;
    const __bf16* Wg = W + (size_t)(bn * BN + sr) * K + scs * 8;
    __bf16* Asd = &As[0][0] + sr * 64 + sc * 8;
    __bf16* Bsd = &Bs[0][0] + sr * 64 + sc * 8;

    auto stage = [&](int t, int h) {
        const int k0 = t * 64;
#pragma unroll
        for (int ra = 0; ra < 4; ++ra)
            load_lds16(Ag + (size_t)(ra * 64) * K + k0,
                       Asd + h * 16384 + ra * 4096);
#pragma unroll
        for (int rb = 0; rb < NI; ++rb)
            load_lds16(Wg + (size_t)(rb * 64) * K + k0,
                       Bsd + h * (BN * 64) + rb * 4096);
    };
    auto wait_prev = [&]() {  // keep the (4+NI) just-issued loads in flight
        if constexpr (NI == 4) asm volatile("s_waitcnt vmcnt(8)" ::: "memory");
        else                   asm volatile("s_waitcnt vmcnt(6)" ::: "memory");
    };

    const int NT = K / 64;

    stage(0, 0);
    stage(1, 1);
    wait_prev();   // tile 0 (oldest 4+NI loads) landed; tile 1 in flight
    asm volatile("" ::: "memory");
    __builtin_amdgcn_s_barrier();
    asm volatile("" ::: "memory");

    for (int t = 0; t < NT; ++t) {
        const int h = t & 1;
        const __bf16* Ab = &As[h][0];
        const __bf16* Bb = &Bs[h][0];

        bf16x8 bfr[NI][2];
#pragma unroll
        for (int ph = 0; ph < 4; ++ph) {
            bf16x8 af[2][2];
#pragma unroll
            for (int j = 0; j < 2; ++j)
#pragma unroll
                for (int ks = 0; ks < 2; ++ks)
                    af[j][ks] = *(const bf16x8*)(
                        Ab + (wm2 * 128 + (ph * 2 + j) * 16 + l16) * 64 +
                        (((ks * 4 + quad) ^ (l16 & 7)) * 8));
            if (ph == 0) {
#pragma unroll
                for (int ni = 0; ni < NI; ++ni)
#pragma unroll
                    for (int ks = 0; ks < 2; ++ks)
                        bfr[ni][ks] = *(const bf16x8*)(
                            Bb + (wn4 * 16 * NI + ni * 16 + l16) * 64 +
                            (((ks * 4 + quad) ^ (l16 & 7)) * 8));
            }
            asm volatile("" ::: "memory");
            __builtin_amdgcn_s_barrier();
            asm volatile("" ::: "memory");
            __builtin_amdgcn_s_setprio(1);
#pragma unroll
            for (int j = 0; j < 2; ++j)
#pragma unroll
                for (int ni = 0; ni < NI; ++ni)
#pragma unroll
                    for (int ks = 0; ks < 2; ++ks)
                        acc[ph * 2 + j][ni] = __builtin_amdgcn_mfma_f32_16x16x32_bf16(
                            af[j][ks], bfr[ni][ks], acc[ph * 2 + j][ni], 0, 0, 0);
            __builtin_amdgcn_s_setprio(0);
            asm volatile("" ::: "memory");
            __builtin_amdgcn_s_barrier();   // buf[h] reads done after last phase
            asm volatile("" ::: "memory");
        }

        if (t + 2 < NT) {
            stage(t + 2, h);   // buf[h] freed by the phase-3 trailing barrier
            wait_prev();       // completes tile t+1's loads; t+2 stays in flight
        } else if (t + 1 < NT) {
            asm volatile("s_waitcnt vmcnt(0)" ::: "memory");
        } else {
            break;             // last tile computed; nothing outstanding
        }
        asm volatile("" ::: "memory");
        __builtin_amdgcn_s_barrier();   // buf[h^1] fully populated for all waves
        asm volatile("" ::: "memory");
    }

    // epilogue: C/D layout col=l16, row=quad*4+r
#pragma unroll
    for (int mi = 0; mi < 8; ++mi) {
#pragma unroll
        for (int r = 0; r < 4; ++r) {
            int row = bm * 256 + wm2 * 128 + mi * 16 + quad * 4 + r;
            OutT* Cp = C + (size_t)row * N + bn * BN + wn4 * 16 * NI + l16;
#pragma unroll
            for (int ni = 0; ni < NI; ++ni)
                Cp[ni * 16] = (OutT)acc[mi][ni][r];
        }
    }
}

// ---------------------------------------------------------------------------
// Per-head RMSNorm + RoPE (+ q_gain).  One wave per 128-elem head row.
// q: [B*T][2048] (16 heads).  kv: [B*T][1024], cols 0..511 = k heads.
// ---------------------------------------------------------------------------
__global__ __launch_bounds__(256) void qk_norm_rope(
    __bf16* __restrict__ q, __bf16* __restrict__ kv,
    const float* __restrict__ q_gain)
{
    const int row = blockIdx.x * 4 + (threadIdx.x >> 6);
    const int lane = threadIdx.x & 63;
    const int BTH = 4 * 2048 * 16;

    __bf16* base;
    int t;
    float gain;
    if (row < BTH) {
        int bt = row >> 4, h = row & 15;
        base = q + (size_t)bt * 2048 + h * 128;
        t = bt & 2047;
        gain = q_gain[h];
    } else {
        int r2 = row - BTH;
        int bt = r2 >> 2, kvh = r2 & 3;
        base = kv + (size_t)bt * 1024 + kvh * 128;
        t = bt & 2047;
        gain = 1.0f;
    }

    float x0 = (float)base[lane];        // d = lane
    float x1 = (float)base[lane + 64];   // d = lane + 64

    float ss = x0 * x0 + x1 * x1;
#pragma unroll
    for (int off = 32; off; off >>= 1) ss += __shfl_xor(ss, off);
    float inv = rsqrtf(ss * (1.0f / 128.0f) + 1.1920928955078125e-07f);
    x0 *= inv; x1 *= inv;

    float freq = exp2f(-(float)lane * 0.20762050593046013f);
    float ang = (float)t * freq;
    float s, c;
    sincosf(ang, &s, &c);
    float o0 = x0 * c - x1 * s;
    float o1 = x1 * c + x0 * s;
    base[lane]      = (__bf16)(o0 * gain);
    base[lane + 64] = (__bf16)(o1 * gain);
}

// ---------------------------------------------------------------------------
// V transpose: vt[b][c][t] = kv[b][t][512 + c]   (c = kvh*128+d in [0,512))
// ---------------------------------------------------------------------------
__global__ __launch_bounds__(256) void transpose_v(
    const __bf16* __restrict__ kv, __bf16* __restrict__ vtout)
{
    __shared__ __bf16 tile[64][65];
    const int b = blockIdx.z;
    const int t0 = blockIdx.x * 64, c0 = blockIdx.y * 64;
    const __bf16* vb = kv + (size_t)b * 2048 * 1024 + 512;
    __bf16* vtb = vtout + (size_t)b * 512 * 2048;
    const int j = threadIdx.x & 63;
    const int r0 = threadIdx.x >> 6;
#pragma unroll
    for (int i = 0; i < 16; ++i) {
        int r = r0 + i * 4;
        tile[r][j] = vb[(size_t)(t0 + r) * 1024 + c0 + j];
    }
    __syncthreads();
#pragma unroll
    for (int i = 0; i < 16; ++i) {
        int r = r0 + i * 4;
        vtb[(size_t)(c0 + r) * 2048 + t0 + j] = tile[j][r];
    }
}

// ---------------------------------------------------------------------------
// Flash attention (causal, GQA).  Block = (bh, qtile128), 256 threads.
// Fixed-max softmax, XOR-swizzled LDS, Q in regs, double-buffered K/V with
// counted-vmcnt prefetch.  The two 64-row q-passes are fused so each K/V
// fragment ds_read feeds two MFMAs (LDS-read traffic per MFMA halved).
// ---------------------------------------------------------------------------
__global__ __launch_bounds__(256, 2) void attn(
    const __bf16* __restrict__ q, const __bf16* __restrict__ kv,
    const __bf16* __restrict__ vt, __bf16* __restrict__ y,
    const float* __restrict__ q_gain)
{
    const int qt = 15 - blockIdx.y;  // big blocks launch first
    const int bh = blockIdx.x;
    const int b = bh >> 4, h = bh & 15, kvh = h >> 2;
    const int tid = threadIdx.x;
    const int wave = tid >> 6, lane = tid & 63;
    const int quad = lane >> 4, l16 = lane & 15;

    __shared__ __bf16 Ks[2][64 * 128];    // [kv_row][d]  chunk c at c^(row&15)
    __shared__ __bf16 Vts[2][128 * 64];   // [d][kv_row]  chunk c at c^(row&7)
    __shared__ __bf16 Ps[2][4 * 16 * 64]; // per-pass per-wave [qrow][kv]

    const int qt0 = qt * 128;
    const int wq = wave * 16;   // this wave's 16 q-rows within a 64-row pass

    // Q fragments straight from global (A-layout: 8 contiguous bf16 / lane)
    bf16x8 qf[2][4];
#pragma unroll
    for (int p = 0; p < 2; ++p) {
        const size_t qrow =
            ((size_t)b * 2048 + qt0 + p * 64 + wq + l16) * 2048 + h * 128;
#pragma unroll
        for (int t = 0; t < 4; ++t)
            qf[p][t] = *(const bf16x8*)(q + qrow + t * 32 + quad * 8);
    }

    f32x4 oacc[2][8] = {};
    float lsum[2][4] = {};

    const float sm_scale = 0.12754635f;          // 1/sqrt(128) * log2(e)
    const float mfix = 11.5f * fabsf(q_gain[h]); // >= max possible score

    const size_t kbase = (size_t)b * 2048 * 1024 + kvh * 128;      // stride 1024
    const size_t vtbase = (size_t)(b * 4 + kvh) * 128 * 2048;      // stride 2048

    const int rowK = lane >> 4, pcK = lane & 15;
    const int rowV = lane >> 3, pcV = lane & 7;

    const int nj = 2 * qt + 2;   // 64-wide kv tiles covering [0, qt0+128)

    // prologue: stage tile 0 into buf 0 (8 loads/wave)
    {
#pragma unroll
        for (int r = 0; r < 4; ++r) {
            int rrK = (r * 4 + wave) * 4 + rowK;
            int cK = pcK ^ (rrK & 15);
            load_lds16(kv + kbase + (size_t)rrK * 1024 + cK * 8,
                       &Ks[0][(r * 4 + wave) * 512]);
            int rrV = (r * 4 + wave) * 8 + rowV;
            int cV = pcV ^ (rrV & 7);
            load_lds16(vt + vtbase + (size_t)rrV * 2048 + cV * 8,
                       &Vts[0][(r * 4 + wave) * 512]);
        }
    }

    for (int jt = 0; jt < nj; ++jt) {
        const int cur = jt & 1;

        // all waves done reading buf[cur^1] -> safe to overwrite it
        asm volatile("" ::: "memory");
        __builtin_amdgcn_s_barrier();
        asm volatile("" ::: "memory");

        if (jt + 1 < nj) {
            const int j0n = (jt + 1) * 64;
#pragma unroll
            for (int r = 0; r < 4; ++r) {
                int rrK = (r * 4 + wave) * 4 + rowK;
                int cK = pcK ^ (rrK & 15);
                load_lds16(kv + kbase + (size_t)(j0n + rrK) * 1024 + cK * 8,
                           &Ks[cur ^ 1][(r * 4 + wave) * 512]);
                int rrV = (r * 4 + wave) * 8 + rowV;
                int cV = pcV ^ (rrV & 7);
                load_lds16(vt + vtbase + (size_t)rrV * 2048 + j0n + cV * 8,
                           &Vts[cur ^ 1][(r * 4 + wave) * 512]);
            }
            // wait only for the PREVIOUS stage's 8 loads (buf[cur]); the 8
            // just-issued prefetch loads stay in flight across the barrier.
            asm volatile("s_waitcnt vmcnt(8)" ::: "memory");
        } else {
            asm volatile("s_waitcnt vmcnt(0)" ::: "memory");
        }

        asm volatile("" ::: "memory");
        __builtin_amdgcn_s_barrier();   // buf[cur] fully populated for all waves
        asm volatile("" ::: "memory");

        const __bf16* Kc = Ks[cur];
        const __bf16* Vc = Vts[cur];

        // S strips for BOTH passes, sharing each K-frag read
        f32x4 sacc[2][4] = {};
        __builtin_amdgcn_s_setprio(1);
#pragma unroll
        for (int nt = 0; nt < 4; ++nt)
#pragma unroll
            for (int t = 0; t < 4; ++t) {
                bf16x8 kf = *(const bf16x8*)(
                    Kc + (nt * 16 + l16) * 128 + ((t * 4 + quad) ^ l16) * 8);
                sacc[0][nt] = __builtin_amdgcn_mfma_f32_16x16x32_bf16(
                    qf[0][t], kf, sacc[0][nt], 0, 0, 0);
                sacc[1][nt] = __builtin_amdgcn_mfma_f32_16x16x32_bf16(
                    qf[1][t], kf, sacc[1][nt], 0, 0, 0);
            }
        __builtin_amdgcn_s_setprio(0);

        if (jt >= 2 * qt) {  // last two tiles: causal mask
            const int dj = (jt - 2 * qt) * 64;
#pragma unroll
            for (int p = 0; p < 2; ++p) {
                const int rel = p * 64 + wq + quad * 4 - dj;  // + r
#pragma unroll
                for (int nt = 0; nt < 4; ++nt) {
                    int kg = nt * 16 + l16;
#pragma unroll
                    for (int r = 0; r < 4; ++r)
                        if (kg > rel + r) sacc[p][nt][r] = -3.0e38f;
                }
            }
        }

        // fixed-max exp; per-lane partial row sums; P -> LDS (swizzled)
#pragma unroll
        for (int p = 0; p < 2; ++p) {
            __bf16* Pw = &Ps[p][0] + wave * 1024;
#pragma unroll
            for (int nt = 0; nt < 4; ++nt)
#pragma unroll
                for (int r = 0; r < 4; ++r) {
                    float pv = exp2f((sacc[p][nt][r] - mfix) * sm_scale);
                    lsum[p][r] += pv;
                    int row = quad * 4 + r;
                    int pc = (nt * 2 + (l16 >> 3)) ^ (row & 7);
                    Pw[row * 64 + pc * 8 + (l16 & 7)] = (__bf16)pv;
                }
        }

        // PV for BOTH passes, sharing each V-frag read (per-wave, no barrier)
        __builtin_amdgcn_s_setprio(1);
#pragma unroll
        for (int kt = 0; kt < 2; ++kt) {
            const int pcc = ((kt * 4 + quad) ^ (l16 & 7)) * 8;
            bf16x8 pf0 = *(const bf16x8*)(&Ps[0][0] + wave * 1024 + l16 * 64 + pcc);
            bf16x8 pf1 = *(const bf16x8*)(&Ps[1][0] + wave * 1024 + l16 * 64 + pcc);
#pragma unroll
            for (int vn = 0; vn < 8; ++vn) {
                bf16x8 vf = *(const bf16x8*)(
                    Vc + (vn * 16 + l16) * 64 + pcc);
                oacc[0][vn] = __builtin_amdgcn_mfma_f32_16x16x32_bf16(
                    pf0, vf, oacc[0][vn], 0, 0, 0);
                oacc[1][vn] = __builtin_amdgcn_mfma_f32_16x16x32_bf16(
                    pf1, vf, oacc[1][vn], 0, 0, 0);
            }
        }
        __builtin_amdgcn_s_setprio(0);
    }

    // final l reduction across the 16 lanes holding each row + epilogue
#pragma unroll
    for (int p = 0; p < 2; ++p) {
#pragma unroll
        for (int r = 0; r < 4; ++r)
#pragma unroll
            for (int off = 8; off; off >>= 1)
                lsum[p][r] += __shfl_xor(lsum[p][r], off);

        const size_t ybase =
            ((size_t)b * 2048 + qt0 + p * 64 + wq) * 2048 + h * 128;
#pragma unroll
        for (int r = 0; r < 4; ++r) {
            float inv = 1.0f / lsum[p][r];
            __bf16* yp = y + ybase + (size_t)(quad * 4 + r) * 2048 + l16;
#pragma unroll
            for (int vn = 0; vn < 8; ++vn)
                yp[vn * 16] = (__bf16)(oacc[p][vn][r] * inv);
        }
    }
}

// ---------------------------------------------------------------------------
extern "C" void kernel_launch(void* const* d_in, const int* in_sizes, int n_in,
                              void* d_out, int out_size, void* d_ws, size_t ws_size,
                              hipStream_t stream) {
    const float* x     = (const float*)d_in[0];
    const float* Wq    = (const float*)d_in[1];
    const float* Wk    = (const float*)d_in[2];
    const float* Wv    = (const float*)d_in[3];
    const float* Wproj = (const float*)d_in[4];
    const float* qgain = (const float*)d_in[5];
    float* outp = (float*)d_out;

    // workspace layout (bf16 elems)
    __bf16* xb  = (__bf16*)d_ws;          // 16777216
    __bf16* Wqb = xb  + 16777216;         // 4194304
    __bf16* Wkb = Wqb + 4194304;          // 1048576  (Wkb+Wvb = fused [1024][2048])
    __bf16* Wvb = Wkb + 1048576;          // 1048576
    __bf16* Wpb = Wvb + 1048576;          // 4194304
    __bf16* q   = Wpb + 4194304;          // 16777216
    __bf16* kvb = q   + 16777216;         // 8388608  [4*2048][1024]: k|v fused
    __bf16* vt  = kvb + 8388608;          // 4194304  [4][512][2048]
    __bf16* y   = q;                      // alias: 1:1 tile correspondence, safe

    dim3 blk(256);
    cvt_all<<<dim3(27262976 / 1024), blk, 0, stream>>>(x, Wq, Wk, Wv, Wproj, xb);

    // 256-row tiles; N-tile = 256 (NI=4) or 128 (NI=2).  Grid = 256 blocks
    // = 1 block/CU for all three projections.
    gemm256<4, __bf16><<<dim3(8, 32), dim3(512), 0, stream>>>(xb, Wqb, q, 8192, 2048, 2048);
    gemm256<2, __bf16><<<dim3(8, 32), dim3(512), 0, stream>>>(xb, Wkb, kvb, 8192, 1024, 2048);
    qk_norm_rope<<<dim3((4 * 2048 * (16 + 4)) / 4), blk, 0, stream>>>(q, kvb, qgain);
    transpose_v<<<dim3(32, 8, 4), blk, 0, stream>>>(kvb, vt);
    attn<<<dim3(64, 16), blk, 0, stream>>>(q, kvb, vt, y, qgain);
    gemm256<4, float><<<dim3(8, 32), dim3(512), 0, stream>>>(y, Wpb, outp, 8192, 2048, 2048);
}

// Round 4
// 492.340 us; speedup vs baseline: 1.3290x; 1.0421x over previous
//
#include <hip/hip_runtime.h>
#include <math.h>

// Fused attention block: QKV proj -> per-head RMSNorm -> RoPE (+q_gain) ->
// GQA causal flash attention -> output proj.  FP32 I/O, bf16 MFMA internal.
//
// Shapes: B=4 T=2048 H=16 KVH=4 HD=128 D=2048 KVD=512.
//
// R7 changes vs R6 (attn 125us; GEMMs ~330us at ~520-800TF on the R5
// coarse-phase 256^2 structure -- m196's measured -7..-27% defect):
//  - gemm3buf: 256x256 (or 256x128) tile, BK=32, 8 waves, TRIPLE-buffered
//    LDS rotation.  Iter t computes buf[t%3] while staging tile t+2 into
//    buf[(t+2)%3] (never read this iter) -> stage-issues interleave with
//    ds_reads/MFMAs, ONE barrier + ONE counted vmcnt(4/3) per K-tile
//    (was 9 barriers + bunched stages).  Chunk swizzle c^(r&3)^((r>>2)&3)
//    gives exact 2-way (free) LDS banking; inverse swizzle on the global
//    source, linear LDS dest.  setprio(1) around the 32-MFMA cluster.
//  - attn / cvt_all / norm / transpose unchanged from R6.

typedef float f32x4 __attribute__((ext_vector_type(4)));
typedef __bf16 bf16x8 __attribute__((ext_vector_type(8)));
typedef __bf16 bf16x4 __attribute__((ext_vector_type(4)));

__device__ __forceinline__ void load_lds16(const __bf16* g, __bf16* l) {
    __builtin_amdgcn_global_load_lds(
        (const __attribute__((address_space(1))) void*)g,
        (__attribute__((address_space(3))) void*)l, 16, 0, 0);
}

// ---------------------------------------------------------------------------
// fp32 -> bf16 conversion of all five inputs in one launch.
// dst layout: xb | Wqb | Wkb | Wvb | Wpb  (contiguous, sizes below).
// ---------------------------------------------------------------------------
__global__ __launch_bounds__(256) void cvt_all(
    const float* __restrict__ x,  const float* __restrict__ Wq,
    const float* __restrict__ Wk, const float* __restrict__ Wv,
    const float* __restrict__ Wp, __bf16* __restrict__ dst)
{
    long long i = ((long long)blockIdx.x * 256 + threadIdx.x) * 4;
    if (i >= 27262976LL) return;
    const float* src;
    long long off;
    if (i < 16777216LL)      { src = x;  off = i; }
    else if (i < 20971520LL) { src = Wq; off = i - 16777216LL; }
    else if (i < 22020096LL) { src = Wk; off = i - 20971520LL; }
    else if (i < 23068672LL) { src = Wv; off = i - 22020096LL; }
    else                     { src = Wp; off = i - 23068672LL; }
    float4 v = *(const float4*)(src + off);
    bf16x4 o = {(__bf16)v.x, (__bf16)v.y, (__bf16)v.z, (__bf16)v.w};
    *(bf16x4*)(dst + i) = o;
}

// ---------------------------------------------------------------------------
// GEMM: C[M][N] = A[M][K] * W[N][K]^T   (row-major, bf16 in, OutT out)
// 256x(64*NI) tile, BK=32, 512 threads (8 waves: 2 M-halves x 4 N-quarters;
// per-wave output 128 x 16*NI).  Triple-buffered LDS rotation: compute
// buf[t%3] while staging t+2 into buf[(t+2)%3]; one barrier + one counted
// vmcnt per K-tile; prefetch loads stay in flight across the barrier.
// ---------------------------------------------------------------------------
template <int NI, typename OutT>
__global__ __launch_bounds__(512, 2) void gemm3buf(
    const __bf16* __restrict__ A, const __bf16* __restrict__ W,
    OutT* __restrict__ C, int M, int N, int K)
{
    constexpr int BN = 64 * NI;    // 256 (NI=4) or 128 (NI=2)
    constexpr int WN = 16 * NI;    // per-wave N
    const int bn = blockIdx.x, bm = blockIdx.y;
    const int tid = threadIdx.x;
    const int lane = tid & 63;
    const int wave = tid >> 6;
    const int quad = lane >> 4, l16 = lane & 15;
    const int wm2 = wave >> 2;     // 0..1 : M half (128 rows)
    const int wn4 = wave & 3;      // 0..3 : N quarter

    __shared__ __bf16 As[3][256 * 32];     // 3 x 16KB
    __shared__ __bf16 Bs[3][BN * 32];      // 3 x 16KB (NI=4) / 8KB (NI=2)

    f32x4 acc[8][NI] = {};

    // staging: rows of 32 bf16 = 4 chunks of 16B; 512 threads cover 128 rows
    // per round.  A = 2 rounds, B = NI/2 rounds per K-tile.
    const int sr = tid >> 2;                       // 0..127 row-in-round
    const int sc = tid & 3;                        // dest chunk (linear in tid)
    const int scs = sc ^ (sr & 3) ^ ((sr >> 2) & 3);   // pre-swizzled source
    const int swzq = quad ^ (l16 & 3) ^ ((l16 >> 2) & 3); // read-side swizzle

    const __bf16* Ag = A + (size_t)(bm * 256 + sr) * K + scs * 8;
    const __bf16* Wg = W + (size_t)(bn * BN + sr) * K + scs * 8;
    const int dA = sr * 32 + sc * 8;

    auto stage = [&](int t, int buf) {
        const int k0 = t * 32;
        load_lds16(Ag + k0, &As[buf][dA]);
        load_lds16(Ag + (size_t)128 * K + k0, &As[buf][128 * 32 + dA]);
        load_lds16(Wg + k0, &Bs[buf][dA]);
        if constexpr (NI == 4)
            load_lds16(Wg + (size_t)128 * K + k0, &Bs[buf][128 * 32 + dA]);
    };
    auto wait_cnt = [&]() {   // keep the just-issued tile's loads in flight
        if constexpr (NI == 4) asm volatile("s_waitcnt vmcnt(4)" ::: "memory");
        else                   asm volatile("s_waitcnt vmcnt(3)" ::: "memory");
    };

    const int NT = K / 32;

    stage(0, 0);
    stage(1, 1);
    wait_cnt();   // tile 0 landed; tile 1 in flight
    asm volatile("" ::: "memory");
    __builtin_amdgcn_s_barrier();
    asm volatile("" ::: "memory");

    int cur = 0, nb = 2;
    for (int t = 0; t < NT; ++t) {
        const __bf16* Ab = &As[cur][0];
        const __bf16* Bb = &Bs[cur][0];
        const bool pf = (t + 2 < NT);
        const int k0n = (t + 2) * 32;

        // B fragments, then B prefetch issue
        bf16x8 bfr[NI];
#pragma unroll
        for (int ni = 0; ni < NI; ++ni)
            bfr[ni] = *(const bf16x8*)(
                Bb + (wn4 * WN + ni * 16 + l16) * 32 + swzq * 8);
        if (pf) {
            load_lds16(Wg + k0n, &Bs[nb][dA]);
            if constexpr (NI == 4)
                load_lds16(Wg + (size_t)128 * K + k0n, &Bs[nb][128 * 32 + dA]);
        }

        // A fragments, then A prefetch issue
        bf16x8 af[8];
#pragma unroll
        for (int mi = 0; mi < 8; ++mi)
            af[mi] = *(const bf16x8*)(
                Ab + (wm2 * 128 + mi * 16 + l16) * 32 + swzq * 8);
        if (pf) {
            load_lds16(Ag + k0n, &As[nb][dA]);
            load_lds16(Ag + (size_t)128 * K + k0n, &As[nb][128 * 32 + dA]);
        }

        __builtin_amdgcn_s_setprio(1);
#pragma unroll
        for (int mi = 0; mi < 8; ++mi)
#pragma unroll
            for (int ni = 0; ni < NI; ++ni)
                acc[mi][ni] = __builtin_amdgcn_mfma_f32_16x16x32_bf16(
                    af[mi], bfr[ni], acc[mi][ni], 0, 0, 0);
        __builtin_amdgcn_s_setprio(0);

        if (t + 1 < NT) {
            if (pf) wait_cnt();   // tile t+1 complete; t+2 stays in flight
            else    asm volatile("s_waitcnt vmcnt(0)" ::: "memory");
            asm volatile("" ::: "memory");
            __builtin_amdgcn_s_barrier();
            asm volatile("" ::: "memory");
        }
        cur = (cur + 1 == 3) ? 0 : cur + 1;
        nb  = (nb  + 1 == 3) ? 0 : nb + 1;
    }

    // epilogue: C/D layout col=l16, row=quad*4+r
#pragma unroll
    for (int mi = 0; mi < 8; ++mi) {
#pragma unroll
        for (int r = 0; r < 4; ++r) {
            int row = bm * 256 + wm2 * 128 + mi * 16 + quad * 4 + r;
            OutT* Cp = C + (size_t)row * N + bn * BN + wn4 * WN + l16;
#pragma unroll
            for (int ni = 0; ni < NI; ++ni)
                Cp[ni * 16] = (OutT)acc[mi][ni][r];
        }
    }
}

// ---------------------------------------------------------------------------
// Per-head RMSNorm + RoPE (+ q_gain).  One wave per 128-elem head row.
// q: [B*T][2048] (16 heads).  kv: [B*T][1024], cols 0..511 = k heads.
// ---------------------------------------------------------------------------
__global__ __launch_bounds__(256) void qk_norm_rope(
    __bf16* __restrict__ q, __bf16* __restrict__ kv,
    const float* __restrict__ q_gain)
{
    const int row = blockIdx.x * 4 + (threadIdx.x >> 6);
    const int lane = threadIdx.x & 63;
    const int BTH = 4 * 2048 * 16;

    __bf16* base;
    int t;
    float gain;
    if (row < BTH) {
        int bt = row >> 4, h = row & 15;
        base = q + (size_t)bt * 2048 + h * 128;
        t = bt & 2047;
        gain = q_gain[h];
    } else {
        int r2 = row - BTH;
        int bt = r2 >> 2, kvh = r2 & 3;
        base = kv + (size_t)bt * 1024 + kvh * 128;
        t = bt & 2047;
        gain = 1.0f;
    }

    float x0 = (float)base[lane];        // d = lane
    float x1 = (float)base[lane + 64];   // d = lane + 64

    float ss = x0 * x0 + x1 * x1;
#pragma unroll
    for (int off = 32; off; off >>= 1) ss += __shfl_xor(ss, off);
    float inv = rsqrtf(ss * (1.0f / 128.0f) + 1.1920928955078125e-07f);
    x0 *= inv; x1 *= inv;

    float freq = exp2f(-(float)lane * 0.20762050593046013f);
    float ang = (float)t * freq;
    float s, c;
    sincosf(ang, &s, &c);
    float o0 = x0 * c - x1 * s;
    float o1 = x1 * c + x0 * s;
    base[lane]      = (__bf16)(o0 * gain);
    base[lane + 64] = (__bf16)(o1 * gain);
}

// ---------------------------------------------------------------------------
// V transpose: vt[b][c][t] = kv[b][t][512 + c]   (c = kvh*128+d in [0,512))
// ---------------------------------------------------------------------------
__global__ __launch_bounds__(256) void transpose_v(
    const __bf16* __restrict__ kv, __bf16* __restrict__ vtout)
{
    __shared__ __bf16 tile[64][65];
    const int b = blockIdx.z;
    const int t0 = blockIdx.x * 64, c0 = blockIdx.y * 64;
    const __bf16* vb = kv + (size_t)b * 2048 * 1024 + 512;
    __bf16* vtb = vtout + (size_t)b * 512 * 2048;
    const int j = threadIdx.x & 63;
    const int r0 = threadIdx.x >> 6;
#pragma unroll
    for (int i = 0; i < 16; ++i) {
        int r = r0 + i * 4;
        tile[r][j] = vb[(size_t)(t0 + r) * 1024 + c0 + j];
    }
    __syncthreads();
#pragma unroll
    for (int i = 0; i < 16; ++i) {
        int r = r0 + i * 4;
        vtb[(size_t)(c0 + r) * 2048 + t0 + j] = tile[j][r];
    }
}

// ---------------------------------------------------------------------------
// Flash attention (causal, GQA).  Block = (bh, qtile128), 256 threads.
// Fixed-max softmax, XOR-swizzled LDS, Q in regs, double-buffered K/V with
// counted-vmcnt prefetch.  The two 64-row q-passes are fused so each K/V
// fragment ds_read feeds two MFMAs (LDS-read traffic per MFMA halved).
// ---------------------------------------------------------------------------
__global__ __launch_bounds__(256, 2) void attn(
    const __bf16* __restrict__ q, const __bf16* __restrict__ kv,
    const __bf16* __restrict__ vt, __bf16* __restrict__ y,
    const float* __restrict__ q_gain)
{
    const int qt = 15 - blockIdx.y;  // big blocks launch first
    const int bh = blockIdx.x;
    const int b = bh >> 4, h = bh & 15, kvh = h >> 2;
    const int tid = threadIdx.x;
    const int wave = tid >> 6, lane = tid & 63;
    const int quad = lane >> 4, l16 = lane & 15;

    __shared__ __bf16 Ks[2][64 * 128];    // [kv_row][d]  chunk c at c^(row&15)
    __shared__ __bf16 Vts[2][128 * 64];   // [d][kv_row]  chunk c at c^(row&7)
    __shared__ __bf16 Ps[2][4 * 16 * 64]; // per-pass per-wave [qrow][kv]

    const int qt0 = qt * 128;
    const int wq = wave * 16;   // this wave's 16 q-rows within a 64-row pass

    // Q fragments straight from global (A-layout: 8 contiguous bf16 / lane)
    bf16x8 qf[2][4];
#pragma unroll
    for (int p = 0; p < 2; ++p) {
        const size_t qrow =
            ((size_t)b * 2048 + qt0 + p * 64 + wq + l16) * 2048 + h * 128;
#pragma unroll
        for (int t = 0; t < 4; ++t)
            qf[p][t] = *(const bf16x8*)(q + qrow + t * 32 + quad * 8);
    }

    f32x4 oacc[2][8] = {};
    float lsum[2][4] = {};

    const float sm_scale = 0.12754635f;          // 1/sqrt(128) * log2(e)
    const float mfix = 11.5f * fabsf(q_gain[h]); // >= max possible score

    const size_t kbase = (size_t)b * 2048 * 1024 + kvh * 128;      // stride 1024
    const size_t vtbase = (size_t)(b * 4 + kvh) * 128 * 2048;      // stride 2048

    const int rowK = lane >> 4, pcK = lane & 15;
    const int rowV = lane >> 3, pcV = lane & 7;

    const int nj = 2 * qt + 2;   // 64-wide kv tiles covering [0, qt0+128)

    // prologue: stage tile 0 into buf 0 (8 loads/wave)
    {
#pragma unroll
        for (int r = 0; r < 4; ++r) {
            int rrK = (r * 4 + wave) * 4 + rowK;
            int cK = pcK ^ (rrK & 15);
            load_lds16(kv + kbase + (size_t)rrK * 1024 + cK * 8,
                       &Ks[0][(r * 4 + wave) * 512]);
            int rrV = (r * 4 + wave) * 8 + rowV;
            int cV = pcV ^ (rrV & 7);
            load_lds16(vt + vtbase + (size_t)rrV * 2048 + cV * 8,
                       &Vts[0][(r * 4 + wave) * 512]);
        }
    }

    for (int jt = 0; jt < nj; ++jt) {
        const int cur = jt & 1;

        // all waves done reading buf[cur^1] -> safe to overwrite it
        asm volatile("" ::: "memory");
        __builtin_amdgcn_s_barrier();
        asm volatile("" ::: "memory");

        if (jt + 1 < nj) {
            const int j0n = (jt + 1) * 64;
#pragma unroll
            for (int r = 0; r < 4; ++r) {
                int rrK = (r * 4 + wave) * 4 + rowK;
                int cK = pcK ^ (rrK & 15);
                load_lds16(kv + kbase + (size_t)(j0n + rrK) * 1024 + cK * 8,
                           &Ks[cur ^ 1][(r * 4 + wave) * 512]);
                int rrV = (r * 4 + wave) * 8 + rowV;
                int cV = pcV ^ (rrV & 7);
                load_lds16(vt + vtbase + (size_t)rrV * 2048 + j0n + cV * 8,
                           &Vts[cur ^ 1][(r * 4 + wave) * 512]);
            }
            // wait only for the PREVIOUS stage's 8 loads (buf[cur]); the 8
            // just-issued prefetch loads stay in flight across the barrier.
            asm volatile("s_waitcnt vmcnt(8)" ::: "memory");
        } else {
            asm volatile("s_waitcnt vmcnt(0)" ::: "memory");
        }

        asm volatile("" ::: "memory");
        __builtin_amdgcn_s_barrier();   // buf[cur] fully populated for all waves
        asm volatile("" ::: "memory");

        const __bf16* Kc = Ks[cur];
        const __bf16* Vc = Vts[cur];

        // S strips for BOTH passes, sharing each K-frag read
        f32x4 sacc[2][4] = {};
        __builtin_amdgcn_s_setprio(1);
#pragma unroll
        for (int nt = 0; nt < 4; ++nt)
#pragma unroll
            for (int t = 0; t < 4; ++t) {
                bf16x8 kf = *(const bf16x8*)(
                    Kc + (nt * 16 + l16) * 128 + ((t * 4 + quad) ^ l16) * 8);
                sacc[0][nt] = __builtin_amdgcn_mfma_f32_16x16x32_bf16(
                    qf[0][t], kf, sacc[0][nt], 0, 0, 0);
                sacc[1][nt] = __builtin_amdgcn_mfma_f32_16x16x32_bf16(
                    qf[1][t], kf, sacc[1][nt], 0, 0, 0);
            }
        __builtin_amdgcn_s_setprio(0);

        if (jt >= 2 * qt) {  // last two tiles: causal mask
            const int dj = (jt - 2 * qt) * 64;
#pragma unroll
            for (int p = 0; p < 2; ++p) {
                const int rel = p * 64 + wq + quad * 4 - dj;  // + r
#pragma unroll
                for (int nt = 0; nt < 4; ++nt) {
                    int kg = nt * 16 + l16;
#pragma unroll
                    for (int r = 0; r < 4; ++r)
                        if (kg > rel + r) sacc[p][nt][r] = -3.0e38f;
                }
            }
        }

        // fixed-max exp; per-lane partial row sums; P -> LDS (swizzled)
#pragma unroll
        for (int p = 0; p < 2; ++p) {
            __bf16* Pw = &Ps[p][0] + wave * 1024;
#pragma unroll
            for (int nt = 0; nt < 4; ++nt)
#pragma unroll
                for (int r = 0; r < 4; ++r) {
                    float pv = exp2f((sacc[p][nt][r] - mfix) * sm_scale);
                    lsum[p][r] += pv;
                    int row = quad * 4 + r;
                    int pc = (nt * 2 + (l16 >> 3)) ^ (row & 7);
                    Pw[row * 64 + pc * 8 + (l16 & 7)] = (__bf16)pv;
                }
        }

        // PV for BOTH passes, sharing each V-frag read (per-wave, no barrier)
        __builtin_amdgcn_s_setprio(1);
#pragma unroll
        for (int kt = 0; kt < 2; ++kt) {
            const int pcc = ((kt * 4 + quad) ^ (l16 & 7)) * 8;
            bf16x8 pf0 = *(const bf16x8*)(&Ps[0][0] + wave * 1024 + l16 * 64 + pcc);
            bf16x8 pf1 = *(const bf16x8*)(&Ps[1][0] + wave * 1024 + l16 * 64 + pcc);
#pragma unroll
            for (int vn = 0; vn < 8; ++vn) {
                bf16x8 vf = *(const bf16x8*)(
                    Vc + (vn * 16 + l16) * 64 + pcc);
                oacc[0][vn] = __builtin_amdgcn_mfma_f32_16x16x32_bf16(
                    pf0, vf, oacc[0][vn], 0, 0, 0);
                oacc[1][vn] = __builtin_amdgcn_mfma_f32_16x16x32_bf16(
                    pf1, vf, oacc[1][vn], 0, 0, 0);
            }
        }
        __builtin_amdgcn_s_setprio(0);
    }

    // final l reduction across the 16 lanes holding each row + epilogue
#pragma unroll
    for (int p = 0; p < 2; ++p) {
#pragma unroll
        for (int r = 0; r < 4; ++r)
#pragma unroll
            for (int off = 8; off; off >>= 1)
                lsum[p][r] += __shfl_xor(lsum[p][r], off);

        const size_t ybase =
            ((size_t)b * 2048 + qt0 + p * 64 + wq) * 2048 + h * 128;
#pragma unroll
        for (int r = 0; r < 4; ++r) {
            float inv = 1.0f / lsum[p][r];
            __bf16* yp = y + ybase + (size_t)(quad * 4 + r) * 2048 + l16;
#pragma unroll
            for (int vn = 0; vn < 8; ++vn)
                yp[vn * 16] = (__bf16)(oacc[p][vn][r] * inv);
        }
    }
}

// ---------------------------------------------------------------------------
extern "C" void kernel_launch(void* const* d_in, const int* in_sizes, int n_in,
                              void* d_out, int out_size, void* d_ws, size_t ws_size,
                              hipStream_t stream) {
    const float* x     = (const float*)d_in[0];
    const float* Wq    = (const float*)d_in[1];
    const float* Wk    = (const float*)d_in[2];
    const float* Wv    = (const float*)d_in[3];
    const float* Wproj = (const float*)d_in[4];
    const float* qgain = (const float*)d_in[5];
    float* outp = (float*)d_out;

    // workspace layout (bf16 elems)
    __bf16* xb  = (__bf16*)d_ws;          // 16777216
    __bf16* Wqb = xb  + 16777216;         // 4194304
    __bf16* Wkb = Wqb + 4194304;          // 1048576  (Wkb+Wvb = fused [1024][2048])
    __bf16* Wvb = Wkb + 1048576;          // 1048576
    __bf16* Wpb = Wvb + 1048576;          // 4194304
    __bf16* q   = Wpb + 4194304;          // 16777216
    __bf16* kvb = q   + 16777216;         // 8388608  [4*2048][1024]: k|v fused
    __bf16* vt  = kvb + 8388608;          // 4194304  [4][512][2048]
    __bf16* y   = q;                      // alias: 1:1 tile correspondence, safe

    dim3 blk(256);
    cvt_all<<<dim3(27262976 / 1024), blk, 0, stream>>>(x, Wq, Wk, Wv, Wproj, xb);

    // 256-row tiles; N-tile = 256 (NI=4) or 128 (NI=2).  Grid = 256 blocks.
    gemm3buf<4, __bf16><<<dim3(8, 32), dim3(512), 0, stream>>>(xb, Wqb, q, 8192, 2048, 2048);
    gemm3buf<2, __bf16><<<dim3(8, 32), dim3(512), 0, stream>>>(xb, Wkb, kvb, 8192, 1024, 2048);
    qk_norm_rope<<<dim3((4 * 2048 * (16 + 4)) / 4), blk, 0, stream>>>(q, kvb, qgain);
    transpose_v<<<dim3(32, 8, 4), blk, 0, stream>>>(kvb, vt);
    attn<<<dim3(64, 16), blk, 0, stream>>>(q, kvb, vt, y, qgain);
    gemm3buf<4, float><<<dim3(8, 32), dim3(512), 0, stream>>>(y, Wpb, outp, 8192, 2048, 2048);
}

// Round 5
// 472.746 us; speedup vs baseline: 1.3841x; 1.0414x over previous
//
#include <hip/hip_runtime.h>
#include <math.h>

// Fused attention block: QKV proj -> per-head RMSNorm -> RoPE (+q_gain) ->
// GQA causal flash attention -> output proj.  FP32 I/O, bf16 MFMA internal.
//
// Shapes: B=4 T=2048 H=16 KVH=4 HD=128 D=2048 KVD=512.
//
// R8 changes vs R7 (GEMMs ~320us ~ 540TF; derived memory-path-bound:
// ~900MB/GEMM through L2/L3 at ~4.4TB/s, old XCD mapping streamed ALL of
// A into every XCD's L2):
//  - gemm4buf: grid flipped to (bm, bn) -> XCD = bm%8 (T1): the 8 same-bm
//    blocks per XCD share the A-panel K-window (fetched once per XCD);
//    per-GEMM L3 traffic ~276 -> ~100MB.
//  - 4-buffer LDS rotation (128KB): 2 full tiles in flight behind the
//    current one (vmcnt(8)/NI=4, vmcnt(6)/NI=2) to cover L3/HBM latency
//    that the 1-tile-ahead R7 rotation left exposed.
//  - qk_norm_rope: __sincosf (bf16 output, fast path).
//  - attn / cvt_all / transpose unchanged.

typedef float f32x4 __attribute__((ext_vector_type(4)));
typedef __bf16 bf16x8 __attribute__((ext_vector_type(8)));
typedef __bf16 bf16x4 __attribute__((ext_vector_type(4)));

__device__ __forceinline__ void load_lds16(const __bf16* g, __bf16* l) {
    __builtin_amdgcn_global_load_lds(
        (const __attribute__((address_space(1))) void*)g,
        (__attribute__((address_space(3))) void*)l, 16, 0, 0);
}

// ---------------------------------------------------------------------------
// fp32 -> bf16 conversion of all five inputs in one launch.
// dst layout: xb | Wqb | Wkb | Wvb | Wpb  (contiguous, sizes below).
// ---------------------------------------------------------------------------
__global__ __launch_bounds__(256) void cvt_all(
    const float* __restrict__ x,  const float* __restrict__ Wq,
    const float* __restrict__ Wk, const float* __restrict__ Wv,
    const float* __restrict__ Wp, __bf16* __restrict__ dst)
{
    long long i = ((long long)blockIdx.x * 256 + threadIdx.x) * 4;
    if (i >= 27262976LL) return;
    const float* src;
    long long off;
    if (i < 16777216LL)      { src = x;  off = i; }
    else if (i < 20971520LL) { src = Wq; off = i - 16777216LL; }
    else if (i < 22020096LL) { src = Wk; off = i - 20971520LL; }
    else if (i < 23068672LL) { src = Wv; off = i - 22020096LL; }
    else                     { src = Wp; off = i - 23068672LL; }
    float4 v = *(const float4*)(src + off);
    bf16x4 o = {(__bf16)v.x, (__bf16)v.y, (__bf16)v.z, (__bf16)v.w};
    *(bf16x4*)(dst + i) = o;
}

// ---------------------------------------------------------------------------
// GEMM: C[M][N] = A[M][K] * W[N][K]^T   (row-major, bf16 in, OutT out)
// 256x(64*NI) tile, BK=32, 512 threads (8 waves: 2 M-halves x 4 N-quarters;
// per-wave output 128 x 16*NI).  QUAD-buffered LDS rotation: compute
// buf[t&3] while tiles t+1..t+3 stream in; one barrier + one counted
// vmcnt per K-tile (2 tiles stay in flight across the barrier).
// Grid is (bm, bn): bm fastest -> XCD = bm%8 -> same-XCD blocks share the
// A panel (L2 hit), each streams its own B panel once.
// ---------------------------------------------------------------------------
template <int NI, typename OutT>
__global__ __launch_bounds__(512, 2) void gemm4buf(
    const __bf16* __restrict__ A, const __bf16* __restrict__ W,
    OutT* __restrict__ C, int M, int N, int K)
{
    constexpr int BN = 64 * NI;    // 256 (NI=4) or 128 (NI=2)
    constexpr int WN = 16 * NI;    // per-wave N
    const int bm = blockIdx.x, bn = blockIdx.y;   // bm-major: XCD = bm%8
    const int tid = threadIdx.x;
    const int lane = tid & 63;
    const int wave = tid >> 6;
    const int quad = lane >> 4, l16 = lane & 15;
    const int wm2 = wave >> 2;     // 0..1 : M half (128 rows)
    const int wn4 = wave & 3;      // 0..3 : N quarter

    __shared__ __bf16 As[4][256 * 32];     // 4 x 16KB
    __shared__ __bf16 Bs[4][BN * 32];      // 4 x 16KB (NI=4) / 8KB (NI=2)

    f32x4 acc[8][NI] = {};

    // staging: rows of 32 bf16 = 4 chunks of 16B; 512 threads cover 128 rows
    // per round.  A = 2 rounds, B = NI/2 rounds per K-tile.
    const int sr = tid >> 2;                       // 0..127 row-in-round
    const int sc = tid & 3;                        // dest chunk (linear in tid)
    const int scs = sc ^ (sr & 3) ^ ((sr >> 2) & 3);   // pre-swizzled source
    const int swzq = quad ^ (l16 & 3) ^ ((l16 >> 2) & 3); // read-side swizzle

    const __bf16* Ag = A + (size_t)(bm * 256 + sr) * K + scs * 8;
    const __bf16* Wg = W + (size_t)(bn * BN + sr) * K + scs * 8;
    const int dA = sr * 32 + sc * 8;

    auto stageB = [&](int t) {
        const int k0 = t * 32, buf = t & 3;
        load_lds16(Wg + k0, &Bs[buf][dA]);
        if constexpr (NI == 4)
            load_lds16(Wg + (size_t)128 * K + k0, &Bs[buf][128 * 32 + dA]);
    };
    auto stageA = [&](int t) {
        const int k0 = t * 32, buf = t & 3;
        load_lds16(Ag + k0, &As[buf][dA]);
        load_lds16(Ag + (size_t)128 * K + k0, &As[buf][128 * 32 + dA]);
    };
    auto waitAhead = [&](int ahead) {  // ahead = tiles allowed to stay in flight
        if constexpr (NI == 4) {
            if (ahead >= 2)      asm volatile("s_waitcnt vmcnt(8)" ::: "memory");
            else if (ahead == 1) asm volatile("s_waitcnt vmcnt(4)" ::: "memory");
            else                 asm volatile("s_waitcnt vmcnt(0)" ::: "memory");
        } else {
            if (ahead >= 2)      asm volatile("s_waitcnt vmcnt(6)" ::: "memory");
            else if (ahead == 1) asm volatile("s_waitcnt vmcnt(3)" ::: "memory");
            else                 asm volatile("s_waitcnt vmcnt(0)" ::: "memory");
        }
    };

    const int NT = K / 32;

    stageB(0); stageA(0);
    stageB(1); stageA(1);
    stageB(2); stageA(2);
    waitAhead(2);   // tile 0 landed; tiles 1,2 in flight
    asm volatile("" ::: "memory");
    __builtin_amdgcn_s_barrier();
    asm volatile("" ::: "memory");

    for (int t = 0; t < NT; ++t) {
        const __bf16* Ab = &As[t & 3][0];
        const __bf16* Bb = &Bs[t & 3][0];
        const bool pf = (t + 3 < NT);

        // B fragments, then B prefetch issue (tile t+3 -> buf (t+3)&3,
        // which was read at iter t-1: reads drained before last barrier)
        bf16x8 bfr[NI];
#pragma unroll
        for (int ni = 0; ni < NI; ++ni)
            bfr[ni] = *(const bf16x8*)(
                Bb + (wn4 * WN + ni * 16 + l16) * 32 + swzq * 8);
        if (pf) stageB(t + 3);

        // A fragments, then A prefetch issue
        bf16x8 af[8];
#pragma unroll
        for (int mi = 0; mi < 8; ++mi)
            af[mi] = *(const bf16x8*)(
                Ab + (wm2 * 128 + mi * 16 + l16) * 32 + swzq * 8);
        if (pf) stageA(t + 3);

        __builtin_amdgcn_s_setprio(1);
#pragma unroll
        for (int mi = 0; mi < 8; ++mi)
#pragma unroll
            for (int ni = 0; ni < NI; ++ni)
                acc[mi][ni] = __builtin_amdgcn_mfma_f32_16x16x32_bf16(
                    af[mi], bfr[ni], acc[mi][ni], 0, 0, 0);
        __builtin_amdgcn_s_setprio(0);

        if (t + 1 < NT) {
            const int hi = (t + 3 < NT - 1) ? (t + 3) : (NT - 1);
            waitAhead(hi - (t + 1));   // tile t+1 complete; rest in flight
            asm volatile("" ::: "memory");
            __builtin_amdgcn_s_barrier();
            asm volatile("" ::: "memory");
        }
    }

    // epilogue: C/D layout col=l16, row=quad*4+r
#pragma unroll
    for (int mi = 0; mi < 8; ++mi) {
#pragma unroll
        for (int r = 0; r < 4; ++r) {
            int row = bm * 256 + wm2 * 128 + mi * 16 + quad * 4 + r;
            OutT* Cp = C + (size_t)row * N + bn * BN + wn4 * WN + l16;
#pragma unroll
            for (int ni = 0; ni < NI; ++ni)
                Cp[ni * 16] = (OutT)acc[mi][ni][r];
        }
    }
}

// ---------------------------------------------------------------------------
// Per-head RMSNorm + RoPE (+ q_gain).  One wave per 128-elem head row.
// q: [B*T][2048] (16 heads).  kv: [B*T][1024], cols 0..511 = k heads.
// ---------------------------------------------------------------------------
__global__ __launch_bounds__(256) void qk_norm_rope(
    __bf16* __restrict__ q, __bf16* __restrict__ kv,
    const float* __restrict__ q_gain)
{
    const int row = blockIdx.x * 4 + (threadIdx.x >> 6);
    const int lane = threadIdx.x & 63;
    const int BTH = 4 * 2048 * 16;

    __bf16* base;
    int t;
    float gain;
    if (row < BTH) {
        int bt = row >> 4, h = row & 15;
        base = q + (size_t)bt * 2048 + h * 128;
        t = bt & 2047;
        gain = q_gain[h];
    } else {
        int r2 = row - BTH;
        int bt = r2 >> 2, kvh = r2 & 3;
        base = kv + (size_t)bt * 1024 + kvh * 128;
        t = bt & 2047;
        gain = 1.0f;
    }

    float x0 = (float)base[lane];        // d = lane
    float x1 = (float)base[lane + 64];   // d = lane + 64

    float ss = x0 * x0 + x1 * x1;
#pragma unroll
    for (int off = 32; off; off >>= 1) ss += __shfl_xor(ss, off);
    float inv = rsqrtf(ss * (1.0f / 128.0f) + 1.1920928955078125e-07f);
    x0 *= inv; x1 *= inv;

    float freq = exp2f(-(float)lane * 0.20762050593046013f);
    float ang = (float)t * freq;
    float s, c;
    __sincosf(ang, &s, &c);
    float o0 = x0 * c - x1 * s;
    float o1 = x1 * c + x0 * s;
    base[lane]      = (__bf16)(o0 * gain);
    base[lane + 64] = (__bf16)(o1 * gain);
}

// ---------------------------------------------------------------------------
// V transpose: vt[b][c][t] = kv[b][t][512 + c]   (c = kvh*128+d in [0,512))
// ---------------------------------------------------------------------------
__global__ __launch_bounds__(256) void transpose_v(
    const __bf16* __restrict__ kv, __bf16* __restrict__ vtout)
{
    __shared__ __bf16 tile[64][65];
    const int b = blockIdx.z;
    const int t0 = blockIdx.x * 64, c0 = blockIdx.y * 64;
    const __bf16* vb = kv + (size_t)b * 2048 * 1024 + 512;
    __bf16* vtb = vtout + (size_t)b * 512 * 2048;
    const int j = threadIdx.x & 63;
    const int r0 = threadIdx.x >> 6;
#pragma unroll
    for (int i = 0; i < 16; ++i) {
        int r = r0 + i * 4;
        tile[r][j] = vb[(size_t)(t0 + r) * 1024 + c0 + j];
    }
    __syncthreads();
#pragma unroll
    for (int i = 0; i < 16; ++i) {
        int r = r0 + i * 4;
        vtb[(size_t)(c0 + r) * 2048 + t0 + j] = tile[j][r];
    }
}

// ---------------------------------------------------------------------------
// Flash attention (causal, GQA).  Block = (bh, qtile128), 256 threads.
// Fixed-max softmax, XOR-swizzled LDS, Q in regs, double-buffered K/V with
// counted-vmcnt prefetch.  The two 64-row q-passes are fused so each K/V
// fragment ds_read feeds two MFMAs (LDS-read traffic per MFMA halved).
// ---------------------------------------------------------------------------
__global__ __launch_bounds__(256, 2) void attn(
    const __bf16* __restrict__ q, const __bf16* __restrict__ kv,
    const __bf16* __restrict__ vt, __bf16* __restrict__ y,
    const float* __restrict__ q_gain)
{
    const int qt = 15 - blockIdx.y;  // big blocks launch first
    const int bh = blockIdx.x;
    const int b = bh >> 4, h = bh & 15, kvh = h >> 2;
    const int tid = threadIdx.x;
    const int wave = tid >> 6, lane = tid & 63;
    const int quad = lane >> 4, l16 = lane & 15;

    __shared__ __bf16 Ks[2][64 * 128];    // [kv_row][d]  chunk c at c^(row&15)
    __shared__ __bf16 Vts[2][128 * 64];   // [d][kv_row]  chunk c at c^(row&7)
    __shared__ __bf16 Ps[2][4 * 16 * 64]; // per-pass per-wave [qrow][kv]

    const int qt0 = qt * 128;
    const int wq = wave * 16;   // this wave's 16 q-rows within a 64-row pass

    // Q fragments straight from global (A-layout: 8 contiguous bf16 / lane)
    bf16x8 qf[2][4];
#pragma unroll
    for (int p = 0; p < 2; ++p) {
        const size_t qrow =
            ((size_t)b * 2048 + qt0 + p * 64 + wq + l16) * 2048 + h * 128;
#pragma unroll
        for (int t = 0; t < 4; ++t)
            qf[p][t] = *(const bf16x8*)(q + qrow + t * 32 + quad * 8);
    }

    f32x4 oacc[2][8] = {};
    float lsum[2][4] = {};

    const float sm_scale = 0.12754635f;          // 1/sqrt(128) * log2(e)
    const float mfix = 11.5f * fabsf(q_gain[h]); // >= max possible score

    const size_t kbase = (size_t)b * 2048 * 1024 + kvh * 128;      // stride 1024
    const size_t vtbase = (size_t)(b * 4 + kvh) * 128 * 2048;      // stride 2048

    const int rowK = lane >> 4, pcK = lane & 15;
    const int rowV = lane >> 3, pcV = lane & 7;

    const int nj = 2 * qt + 2;   // 64-wide kv tiles covering [0, qt0+128)

    // prologue: stage tile 0 into buf 0 (8 loads/wave)
    {
#pragma unroll
        for (int r = 0; r < 4; ++r) {
            int rrK = (r * 4 + wave) * 4 + rowK;
            int cK = pcK ^ (rrK & 15);
            load_lds16(kv + kbase + (size_t)rrK * 1024 + cK * 8,
                       &Ks[0][(r * 4 + wave) * 512]);
            int rrV = (r * 4 + wave) * 8 + rowV;
            int cV = pcV ^ (rrV & 7);
            load_lds16(vt + vtbase + (size_t)rrV * 2048 + cV * 8,
                       &Vts[0][(r * 4 + wave) * 512]);
        }
    }

    for (int jt = 0; jt < nj; ++jt) {
        const int cur = jt & 1;

        // all waves done reading buf[cur^1] -> safe to overwrite it
        asm volatile("" ::: "memory");
        __builtin_amdgcn_s_barrier();
        asm volatile("" ::: "memory");

        if (jt + 1 < nj) {
            const int j0n = (jt + 1) * 64;
#pragma unroll
            for (int r = 0; r < 4; ++r) {
                int rrK = (r * 4 + wave) * 4 + rowK;
                int cK = pcK ^ (rrK & 15);
                load_lds16(kv + kbase + (size_t)(j0n + rrK) * 1024 + cK * 8,
                           &Ks[cur ^ 1][(r * 4 + wave) * 512]);
                int rrV = (r * 4 + wave) * 8 + rowV;
                int cV = pcV ^ (rrV & 7);
                load_lds16(vt + vtbase + (size_t)rrV * 2048 + j0n + cV * 8,
                           &Vts[cur ^ 1][(r * 4 + wave) * 512]);
            }
            // wait only for the PREVIOUS stage's 8 loads (buf[cur]); the 8
            // just-issued prefetch loads stay in flight across the barrier.
            asm volatile("s_waitcnt vmcnt(8)" ::: "memory");
        } else {
            asm volatile("s_waitcnt vmcnt(0)" ::: "memory");
        }

        asm volatile("" ::: "memory");
        __builtin_amdgcn_s_barrier();   // buf[cur] fully populated for all waves
        asm volatile("" ::: "memory");

        const __bf16* Kc = Ks[cur];
        const __bf16* Vc = Vts[cur];

        // S strips for BOTH passes, sharing each K-frag read
        f32x4 sacc[2][4] = {};
        __builtin_amdgcn_s_setprio(1);
#pragma unroll
        for (int nt = 0; nt < 4; ++nt)
#pragma unroll
            for (int t = 0; t < 4; ++t) {
                bf16x8 kf = *(const bf16x8*)(
                    Kc + (nt * 16 + l16) * 128 + ((t * 4 + quad) ^ l16) * 8);
                sacc[0][nt] = __builtin_amdgcn_mfma_f32_16x16x32_bf16(
                    qf[0][t], kf, sacc[0][nt], 0, 0, 0);
                sacc[1][nt] = __builtin_amdgcn_mfma_f32_16x16x32_bf16(
                    qf[1][t], kf, sacc[1][nt], 0, 0, 0);
            }
        __builtin_amdgcn_s_setprio(0);

        if (jt >= 2 * qt) {  // last two tiles: causal mask
            const int dj = (jt - 2 * qt) * 64;
#pragma unroll
            for (int p = 0; p < 2; ++p) {
                const int rel = p * 64 + wq + quad * 4 - dj;  // + r
#pragma unroll
                for (int nt = 0; nt < 4; ++nt) {
                    int kg = nt * 16 + l16;
#pragma unroll
                    for (int r = 0; r < 4; ++r)
                        if (kg > rel + r) sacc[p][nt][r] = -3.0e38f;
                }
            }
        }

        // fixed-max exp; per-lane partial row sums; P -> LDS (swizzled)
#pragma unroll
        for (int p = 0; p < 2; ++p) {
            __bf16* Pw = &Ps[p][0] + wave * 1024;
#pragma unroll
            for (int nt = 0; nt < 4; ++nt)
#pragma unroll
                for (int r = 0; r < 4; ++r) {
                    float pv = exp2f((sacc[p][nt][r] - mfix) * sm_scale);
                    lsum[p][r] += pv;
                    int row = quad * 4 + r;
                    int pc = (nt * 2 + (l16 >> 3)) ^ (row & 7);
                    Pw[row * 64 + pc * 8 + (l16 & 7)] = (__bf16)pv;
                }
        }

        // PV for BOTH passes, sharing each V-frag read (per-wave, no barrier)
        __builtin_amdgcn_s_setprio(1);
#pragma unroll
        for (int kt = 0; kt < 2; ++kt) {
            const int pcc = ((kt * 4 + quad) ^ (l16 & 7)) * 8;
            bf16x8 pf0 = *(const bf16x8*)(&Ps[0][0] + wave * 1024 + l16 * 64 + pcc);
            bf16x8 pf1 = *(const bf16x8*)(&Ps[1][0] + wave * 1024 + l16 * 64 + pcc);
#pragma unroll
            for (int vn = 0; vn < 8; ++vn) {
                bf16x8 vf = *(const bf16x8*)(
                    Vc + (vn * 16 + l16) * 64 + pcc);
                oacc[0][vn] = __builtin_amdgcn_mfma_f32_16x16x32_bf16(
                    pf0, vf, oacc[0][vn], 0, 0, 0);
                oacc[1][vn] = __builtin_amdgcn_mfma_f32_16x16x32_bf16(
                    pf1, vf, oacc[1][vn], 0, 0, 0);
            }
        }
        __builtin_amdgcn_s_setprio(0);
    }

    // final l reduction across the 16 lanes holding each row + epilogue
#pragma unroll
    for (int p = 0; p < 2; ++p) {
#pragma unroll
        for (int r = 0; r < 4; ++r)
#pragma unroll
            for (int off = 8; off; off >>= 1)
                lsum[p][r] += __shfl_xor(lsum[p][r], off);

        const size_t ybase =
            ((size_t)b * 2048 + qt0 + p * 64 + wq) * 2048 + h * 128;
#pragma unroll
        for (int r = 0; r < 4; ++r) {
            float inv = 1.0f / lsum[p][r];
            __bf16* yp = y + ybase + (size_t)(quad * 4 + r) * 2048 + l16;
#pragma unroll
            for (int vn = 0; vn < 8; ++vn)
                yp[vn * 16] = (__bf16)(oacc[p][vn][r] * inv);
        }
    }
}

// ---------------------------------------------------------------------------
extern "C" void kernel_launch(void* const* d_in, const int* in_sizes, int n_in,
                              void* d_out, int out_size, void* d_ws, size_t ws_size,
                              hipStream_t stream) {
    const float* x     = (const float*)d_in[0];
    const float* Wq    = (const float*)d_in[1];
    const float* Wk    = (const float*)d_in[2];
    const float* Wv    = (const float*)d_in[3];
    const float* Wproj = (const float*)d_in[4];
    const float* qgain = (const float*)d_in[5];
    float* outp = (float*)d_out;

    // workspace layout (bf16 elems)
    __bf16* xb  = (__bf16*)d_ws;          // 16777216
    __bf16* Wqb = xb  + 16777216;         // 4194304
    __bf16* Wkb = Wqb + 4194304;          // 1048576  (Wkb+Wvb = fused [1024][2048])
    __bf16* Wvb = Wkb + 1048576;          // 1048576
    __bf16* Wpb = Wvb + 1048576;          // 4194304
    __bf16* q   = Wpb + 4194304;          // 16777216
    __bf16* kvb = q   + 16777216;         // 8388608  [4*2048][1024]: k|v fused
    __bf16* vt  = kvb + 8388608;          // 4194304  [4][512][2048]
    __bf16* y   = q;                      // alias: 1:1 tile correspondence, safe

    dim3 blk(256);
    cvt_all<<<dim3(27262976 / 1024), blk, 0, stream>>>(x, Wq, Wk, Wv, Wproj, xb);

    // 256-row tiles; grid = (bm, bn) so XCD = bm%8 (A-panel L2 sharing).
    gemm4buf<4, __bf16><<<dim3(32, 8), dim3(512), 0, stream>>>(xb, Wqb, q, 8192, 2048, 2048);
    gemm4buf<2, __bf16><<<dim3(32, 8), dim3(512), 0, stream>>>(xb, Wkb, kvb, 8192, 1024, 2048);
    qk_norm_rope<<<dim3((4 * 2048 * (16 + 4)) / 4), blk, 0, stream>>>(q, kvb, qgain);
    transpose_v<<<dim3(32, 8, 4), blk, 0, stream>>>(kvb, vt);
    attn<<<dim3(64, 16), blk, 0, stream>>>(q, kvb, vt, y, qgain);
    gemm4buf<4, float><<<dim3(32, 8), dim3(512), 0, stream>>>(y, Wpb, outp, 8192, 2048, 2048);
}

// Round 6
// 456.242 us; speedup vs baseline: 1.4342x; 1.0362x over previous
//
#include <hip/hip_runtime.h>
#include <math.h>

// Fused attention block: QKV proj -> per-head RMSNorm -> RoPE (+q_gain) ->
// GQA causal flash attention -> output proj.  FP32 I/O, bf16 MFMA internal.
//
// Shapes: B=4 T=2048 H=16 KVH=4 HD=128 D=2048 KVD=512.
//
// R9 changes vs R8 (attn 122us, VALUBusy 50 + MfmaUtil 25 = issue-bound on
// the softmax/P-scatter serial chain; GEMM lane closed after 3x ~20us):
//  - attn: SWAPPED-QK (T12 structure): sacc = mfma(K,Q) = S^T, so each
//    lane holds 4 consecutive kv for ONE qrow.  P packs to u32 bf16-pairs:
//    8 ds_write_b64 replace 32 ds_write_b16 (+32 addr chains, 16 cvts);
//    P-read b128 of u32x4 IS the PV B-fragment.  PV = mfma(V,P) -> O^T;
//    lsum is one scalar/pass/lane; epilogue packs bf16x4 8B stores.
//    LDS ops per jt per wave 68 -> 44.
//  - attn: Q RMSNorm+RoPE+gain fused into the prologue (lane-local math;
//    loads issued before tile-0 staging so both hide).  Norm kernel now
//    processes K rows only (4/20 of its old work); q read-modify-write
//    traffic (67MB) eliminated.
//  - gemm4buf / cvt_all / transpose_v unchanged.

typedef float f32x4 __attribute__((ext_vector_type(4)));
typedef __bf16 bf16x8 __attribute__((ext_vector_type(8)));
typedef __bf16 bf16x4 __attribute__((ext_vector_type(4)));
typedef __bf16 bf16x2 __attribute__((ext_vector_type(2)));

__device__ __forceinline__ void load_lds16(const __bf16* g, __bf16* l) {
    __builtin_amdgcn_global_load_lds(
        (const __attribute__((address_space(1))) void*)g,
        (__attribute__((address_space(3))) void*)l, 16, 0, 0);
}

__device__ __forceinline__ unsigned pack_bf16(float lo, float hi) {
    union { bf16x2 v; unsigned u; } c;
    c.v = bf16x2{(__bf16)lo, (__bf16)hi};
    return c.u;
}

// ---------------------------------------------------------------------------
// fp32 -> bf16 conversion of all five inputs in one launch.
// dst layout: xb | Wqb | Wkb | Wvb | Wpb  (contiguous, sizes below).
// ---------------------------------------------------------------------------
__global__ __launch_bounds__(256) void cvt_all(
    const float* __restrict__ x,  const float* __restrict__ Wq,
    const float* __restrict__ Wk, const float* __restrict__ Wv,
    const float* __restrict__ Wp, __bf16* __restrict__ dst)
{
    long long i = ((long long)blockIdx.x * 256 + threadIdx.x) * 4;
    if (i >= 27262976LL) return;
    const float* src;
    long long off;
    if (i < 16777216LL)      { src = x;  off = i; }
    else if (i < 20971520LL) { src = Wq; off = i - 16777216LL; }
    else if (i < 22020096LL) { src = Wk; off = i - 20971520LL; }
    else if (i < 23068672LL) { src = Wv; off = i - 22020096LL; }
    else                     { src = Wp; off = i - 23068672LL; }
    float4 v = *(const float4*)(src + off);
    bf16x4 o = {(__bf16)v.x, (__bf16)v.y, (__bf16)v.z, (__bf16)v.w};
    *(bf16x4*)(dst + i) = o;
}

// ---------------------------------------------------------------------------
// GEMM: C[M][N] = A[M][K] * W[N][K]^T   (row-major, bf16 in, OutT out)
// 256x(64*NI) tile, BK=32, 512 threads, quad-buffered LDS rotation,
// counted vmcnt, bm-major grid (XCD = bm%8 shares the A panel).
// ---------------------------------------------------------------------------
template <int NI, typename OutT>
__global__ __launch_bounds__(512, 2) void gemm4buf(
    const __bf16* __restrict__ A, const __bf16* __restrict__ W,
    OutT* __restrict__ C, int M, int N, int K)
{
    constexpr int BN = 64 * NI;    // 256 (NI=4) or 128 (NI=2)
    constexpr int WN = 16 * NI;    // per-wave N
    const int bm = blockIdx.x, bn = blockIdx.y;   // bm-major: XCD = bm%8
    const int tid = threadIdx.x;
    const int lane = tid & 63;
    const int wave = tid >> 6;
    const int quad = lane >> 4, l16 = lane & 15;
    const int wm2 = wave >> 2;     // 0..1 : M half (128 rows)
    const int wn4 = wave & 3;      // 0..3 : N quarter

    __shared__ __bf16 As[4][256 * 32];     // 4 x 16KB
    __shared__ __bf16 Bs[4][BN * 32];      // 4 x 16KB (NI=4) / 8KB (NI=2)

    f32x4 acc[8][NI] = {};

    const int sr = tid >> 2;                       // 0..127 row-in-round
    const int sc = tid & 3;                        // dest chunk (linear in tid)
    const int scs = sc ^ (sr & 3) ^ ((sr >> 2) & 3);   // pre-swizzled source
    const int swzq = quad ^ (l16 & 3) ^ ((l16 >> 2) & 3); // read-side swizzle

    const __bf16* Ag = A + (size_t)(bm * 256 + sr) * K + scs * 8;
    const __bf16* Wg = W + (size_t)(bn * BN + sr) * K + scs * 8;
    const int dA = sr * 32 + sc * 8;

    auto stageB = [&](int t) {
        const int k0 = t * 32, buf = t & 3;
        load_lds16(Wg + k0, &Bs[buf][dA]);
        if constexpr (NI == 4)
            load_lds16(Wg + (size_t)128 * K + k0, &Bs[buf][128 * 32 + dA]);
    };
    auto stageA = [&](int t) {
        const int k0 = t * 32, buf = t & 3;
        load_lds16(Ag + k0, &As[buf][dA]);
        load_lds16(Ag + (size_t)128 * K + k0, &As[buf][128 * 32 + dA]);
    };
    auto waitAhead = [&](int ahead) {  // ahead = tiles allowed to stay in flight
        if constexpr (NI == 4) {
            if (ahead >= 2)      asm volatile("s_waitcnt vmcnt(8)" ::: "memory");
            else if (ahead == 1) asm volatile("s_waitcnt vmcnt(4)" ::: "memory");
            else                 asm volatile("s_waitcnt vmcnt(0)" ::: "memory");
        } else {
            if (ahead >= 2)      asm volatile("s_waitcnt vmcnt(6)" ::: "memory");
            else if (ahead == 1) asm volatile("s_waitcnt vmcnt(3)" ::: "memory");
            else                 asm volatile("s_waitcnt vmcnt(0)" ::: "memory");
        }
    };

    const int NT = K / 32;

    stageB(0); stageA(0);
    stageB(1); stageA(1);
    stageB(2); stageA(2);
    waitAhead(2);   // tile 0 landed; tiles 1,2 in flight
    asm volatile("" ::: "memory");
    __builtin_amdgcn_s_barrier();
    asm volatile("" ::: "memory");

    for (int t = 0; t < NT; ++t) {
        const __bf16* Ab = &As[t & 3][0];
        const __bf16* Bb = &Bs[t & 3][0];
        const bool pf = (t + 3 < NT);

        bf16x8 bfr[NI];
#pragma unroll
        for (int ni = 0; ni < NI; ++ni)
            bfr[ni] = *(const bf16x8*)(
                Bb + (wn4 * WN + ni * 16 + l16) * 32 + swzq * 8);
        if (pf) stageB(t + 3);

        bf16x8 af[8];
#pragma unroll
        for (int mi = 0; mi < 8; ++mi)
            af[mi] = *(const bf16x8*)(
                Ab + (wm2 * 128 + mi * 16 + l16) * 32 + swzq * 8);
        if (pf) stageA(t + 3);

        __builtin_amdgcn_s_setprio(1);
#pragma unroll
        for (int mi = 0; mi < 8; ++mi)
#pragma unroll
            for (int ni = 0; ni < NI; ++ni)
                acc[mi][ni] = __builtin_amdgcn_mfma_f32_16x16x32_bf16(
                    af[mi], bfr[ni], acc[mi][ni], 0, 0, 0);
        __builtin_amdgcn_s_setprio(0);

        if (t + 1 < NT) {
            const int hi = (t + 3 < NT - 1) ? (t + 3) : (NT - 1);
            waitAhead(hi - (t + 1));
            asm volatile("" ::: "memory");
            __builtin_amdgcn_s_barrier();
            asm volatile("" ::: "memory");
        }
    }

    // epilogue: C/D layout col=l16, row=quad*4+r
#pragma unroll
    for (int mi = 0; mi < 8; ++mi) {
#pragma unroll
        for (int r = 0; r < 4; ++r) {
            int row = bm * 256 + wm2 * 128 + mi * 16 + quad * 4 + r;
            OutT* Cp = C + (size_t)row * N + bn * BN + wn4 * WN + l16;
#pragma unroll
            for (int ni = 0; ni < NI; ++ni)
                Cp[ni * 16] = (OutT)acc[mi][ni][r];
        }
    }
}

// ---------------------------------------------------------------------------
// K-head RMSNorm + RoPE.  One wave per 128-elem head row.
// kv: [B*T][1024], cols 0..511 = k heads (v heads untouched).
// ---------------------------------------------------------------------------
__global__ __launch_bounds__(256) void k_norm_rope(__bf16* __restrict__ kv)
{
    const int row = blockIdx.x * 4 + (threadIdx.x >> 6);   // B*T*KVH rows
    const int lane = threadIdx.x & 63;
    const int bt = row >> 2, kvh = row & 3;
    __bf16* base = kv + (size_t)bt * 1024 + kvh * 128;
    const int t = bt & 2047;

    float x0 = (float)base[lane];        // d = lane
    float x1 = (float)base[lane + 64];   // d = lane + 64

    float ss = x0 * x0 + x1 * x1;
#pragma unroll
    for (int off = 32; off; off >>= 1) ss += __shfl_xor(ss, off);
    float inv = rsqrtf(ss * (1.0f / 128.0f) + 1.1920928955078125e-07f);
    x0 *= inv; x1 *= inv;

    float freq = exp2f(-(float)lane * 0.20762050593046013f);
    float s, c;
    __sincosf((float)t * freq, &s, &c);
    base[lane]      = (__bf16)(x0 * c - x1 * s);
    base[lane + 64] = (__bf16)(x1 * c + x0 * s);
}

// ---------------------------------------------------------------------------
// V transpose: vt[b][c][t] = kv[b][t][512 + c]   (c = kvh*128+d in [0,512))
// ---------------------------------------------------------------------------
__global__ __launch_bounds__(256) void transpose_v(
    const __bf16* __restrict__ kv, __bf16* __restrict__ vtout)
{
    __shared__ __bf16 tile[64][65];
    const int b = blockIdx.z;
    const int t0 = blockIdx.x * 64, c0 = blockIdx.y * 64;
    const __bf16* vb = kv + (size_t)b * 2048 * 1024 + 512;
    __bf16* vtb = vtout + (size_t)b * 512 * 2048;
    const int j = threadIdx.x & 63;
    const int r0 = threadIdx.x >> 6;
#pragma unroll
    for (int i = 0; i < 16; ++i) {
        int r = r0 + i * 4;
        tile[r][j] = vb[(size_t)(t0 + r) * 1024 + c0 + j];
    }
    __syncthreads();
#pragma unroll
    for (int i = 0; i < 16; ++i) {
        int r = r0 + i * 4;
        vtb[(size_t)(c0 + r) * 2048 + t0 + j] = tile[j][r];
    }
}

// ---------------------------------------------------------------------------
// Flash attention (causal, GQA).  Block = (bh, qtile128), 256 threads.
// Swapped-QK: sacc = mfma(K,Q) = S^T (col=l16=qrow, row=kv).  P packed as
// bf16-pair u32s -> 8 ds_write_b64; P b128 read IS the PV B-fragment.
// PV = mfma(V,P) -> O^T; lsum scalar per lane.  Q norm+rope+gain fused in
// the prologue.  Double-buffered K/V with counted-vmcnt prefetch.
// ---------------------------------------------------------------------------
__global__ __launch_bounds__(256, 2) void attn(
    const __bf16* __restrict__ q, const __bf16* __restrict__ kv,
    const __bf16* __restrict__ vt, __bf16* __restrict__ y,
    const float* __restrict__ q_gain)
{
    const int qt = 15 - blockIdx.y;  // big blocks launch first
    const int bh = blockIdx.x;
    const int b = bh >> 4, h = bh & 15, kvh = h >> 2;
    const int tid = threadIdx.x;
    const int wave = tid >> 6, lane = tid & 63;
    const int quad = lane >> 4, l16 = lane & 15;

    __shared__ __bf16 Ks[2][64 * 128];    // [kv_row][d]  chunk c at c^(row&15)
    __shared__ __bf16 Vts[2][128 * 64];   // [d][kv_row]  chunk c at c^(row&7)
    __shared__ unsigned Ppk[2][4][16 * 32]; // [pass][wave][qrow][kv-pair]

    const int qt0 = qt * 128;
    const int wq = wave * 16;
    const float gain = q_gain[h];

    // ---- Q loads first (latency hides under staging + prologue math) ----
    bf16x8 qraw[2][4];
#pragma unroll
    for (int p = 0; p < 2; ++p) {
        const size_t qrow =
            ((size_t)b * 2048 + qt0 + p * 64 + wq + l16) * 2048 + h * 128;
#pragma unroll
        for (int t = 0; t < 4; ++t)
            qraw[p][t] = *(const bf16x8*)(q + qrow + t * 32 + quad * 8);
    }

    const size_t kbase = (size_t)b * 2048 * 1024 + kvh * 128;      // stride 1024
    const size_t vtbase = (size_t)(b * 4 + kvh) * 128 * 2048;      // stride 2048
    const int rowK = lane >> 4, pcK = lane & 15;
    const int rowV = lane >> 3, pcV = lane & 7;
    const int nj = 2 * qt + 2;   // 64-wide kv tiles covering [0, qt0+128)

    // prologue: stage tile 0 into buf 0 (8 loads/wave)
    {
#pragma unroll
        for (int r = 0; r < 4; ++r) {
            int rrK = (r * 4 + wave) * 4 + rowK;
            int cK = pcK ^ (rrK & 15);
            load_lds16(kv + kbase + (size_t)rrK * 1024 + cK * 8,
                       &Ks[0][(r * 4 + wave) * 512]);
            int rrV = (r * 4 + wave) * 8 + rowV;
            int cV = pcV ^ (rrV & 7);
            load_lds16(vt + vtbase + (size_t)rrV * 2048 + cV * 8,
                       &Vts[0][(r * 4 + wave) * 512]);
        }
    }

    // ---- Q RMSNorm + RoPE + gain (in registers) ----
    bf16x8 qf[2][4];
#pragma unroll
    for (int p = 0; p < 2; ++p) {
        float xv[4][8];
        float ss = 0.f;
#pragma unroll
        for (int t = 0; t < 4; ++t)
#pragma unroll
            for (int j = 0; j < 8; ++j) {
                float f = (float)qraw[p][t][j];
                xv[t][j] = f; ss += f * f;
            }
        ss += __shfl_xor(ss, 16);
        ss += __shfl_xor(ss, 32);
        const float sc = rsqrtf(ss * (1.0f / 128.0f) +
                                1.1920928955078125e-07f) * gain;
        const float trow = (float)(qt0 + p * 64 + wq + l16);
#pragma unroll
        for (int t = 0; t < 2; ++t)
#pragma unroll
            for (int j = 0; j < 8; ++j) {
                const float fr =
                    exp2f(-(float)(t * 32 + quad * 8 + j) * 0.20762050593046013f);
                float s, c;
                __sincosf(trow * fr, &s, &c);
                const float x0 = xv[t][j], x1 = xv[t + 2][j];
                qf[p][t][j]     = (__bf16)((x0 * c - x1 * s) * sc);
                qf[p][t + 2][j] = (__bf16)((x1 * c + x0 * s) * sc);
            }
    }

    f32x4 oacc[2][8] = {};
    float lsum[2] = {0.f, 0.f};
    const float sm_scale = 0.12754635f;          // 1/sqrt(128) * log2(e)
    const float mfix = 11.5f * fabsf(gain);      // >= max possible score

    for (int jt = 0; jt < nj; ++jt) {
        const int cur = jt & 1;

        // all waves done reading buf[cur^1] -> safe to overwrite it
        asm volatile("" ::: "memory");
        __builtin_amdgcn_s_barrier();
        asm volatile("" ::: "memory");

        if (jt + 1 < nj) {
            const int j0n = (jt + 1) * 64;
#pragma unroll
            for (int r = 0; r < 4; ++r) {
                int rrK = (r * 4 + wave) * 4 + rowK;
                int cK = pcK ^ (rrK & 15);
                load_lds16(kv + kbase + (size_t)(j0n + rrK) * 1024 + cK * 8,
                           &Ks[cur ^ 1][(r * 4 + wave) * 512]);
                int rrV = (r * 4 + wave) * 8 + rowV;
                int cV = pcV ^ (rrV & 7);
                load_lds16(vt + vtbase + (size_t)rrV * 2048 + j0n + cV * 8,
                           &Vts[cur ^ 1][(r * 4 + wave) * 512]);
            }
            // wait only for the PREVIOUS stage's 8 loads; the 8 just-issued
            // prefetch loads stay in flight across the barrier.
            asm volatile("s_waitcnt vmcnt(8)" ::: "memory");
        } else {
            asm volatile("s_waitcnt vmcnt(0)" ::: "memory");
        }

        asm volatile("" ::: "memory");
        __builtin_amdgcn_s_barrier();   // buf[cur] fully populated
        asm volatile("" ::: "memory");

        const __bf16* Kc = Ks[cur];
        const __bf16* Vc = Vts[cur];

        // S^T strips for BOTH passes, sharing each K-frag read
        f32x4 sacc[2][4] = {};
        __builtin_amdgcn_s_setprio(1);
#pragma unroll
        for (int nt = 0; nt < 4; ++nt)
#pragma unroll
            for (int t = 0; t < 4; ++t) {
                bf16x8 kf = *(const bf16x8*)(
                    Kc + (nt * 16 + l16) * 128 + ((t * 4 + quad) ^ l16) * 8);
                sacc[0][nt] = __builtin_amdgcn_mfma_f32_16x16x32_bf16(
                    kf, qf[0][t], sacc[0][nt], 0, 0, 0);
                sacc[1][nt] = __builtin_amdgcn_mfma_f32_16x16x32_bf16(
                    kf, qf[1][t], sacc[1][nt], 0, 0, 0);
            }
        __builtin_amdgcn_s_setprio(0);

        if (jt >= 2 * qt) {  // last two tiles: causal mask (kv > qrow)
            const int dj = jt - 2 * qt;
#pragma unroll
            for (int p = 0; p < 2; ++p) {
                const int rel = (p - dj) * 64 + wq + l16;
#pragma unroll
                for (int nt = 0; nt < 4; ++nt) {
                    const int kvb = nt * 16 + quad * 4;
#pragma unroll
                    for (int r = 0; r < 4; ++r)
                        if (kvb + r > rel) sacc[p][nt][r] = -3.0e38f;
                }
            }
        }

        // fixed-max exp; pack bf16 pairs; 1 ds_write_b64 per nt per pass
#pragma unroll
        for (int p = 0; p < 2; ++p) {
            unsigned* Pw = &Ppk[p][wave][0];
            const int wb = l16 * 32 + (quad & 1) * 2;
            float ls = 0.f;
#pragma unroll
            for (int nt = 0; nt < 4; ++nt) {
                float e0 = exp2f((sacc[p][nt][0] - mfix) * sm_scale);
                float e1 = exp2f((sacc[p][nt][1] - mfix) * sm_scale);
                float e2 = exp2f((sacc[p][nt][2] - mfix) * sm_scale);
                float e3 = exp2f((sacc[p][nt][3] - mfix) * sm_scale);
                ls += (e0 + e1) + (e2 + e3);
                uint2 u;
                u.x = pack_bf16(e0, e1);
                u.y = pack_bf16(e2, e3);
                *(uint2*)(Pw + wb + (((nt * 2 + (quad >> 1)) ^ (l16 & 7)) << 2)) = u;
            }
            lsum[p] += ls;
        }

        // PV for BOTH passes; P b128 read is the B-fragment directly
        __builtin_amdgcn_s_setprio(1);
#pragma unroll
        for (int kt = 0; kt < 2; ++kt) {
            const int pcc = (kt * 4 + quad) ^ (l16 & 7);
            union { uint4 u; bf16x8 v; } c0, c1;
            c0.u = *(const uint4*)(&Ppk[0][wave][0] + l16 * 32 + (pcc << 2));
            c1.u = *(const uint4*)(&Ppk[1][wave][0] + l16 * 32 + (pcc << 2));
#pragma unroll
            for (int vn = 0; vn < 8; ++vn) {
                bf16x8 vf = *(const bf16x8*)(
                    Vc + (vn * 16 + l16) * 64 + pcc * 8);
                oacc[0][vn] = __builtin_amdgcn_mfma_f32_16x16x32_bf16(
                    vf, c0.v, oacc[0][vn], 0, 0, 0);
                oacc[1][vn] = __builtin_amdgcn_mfma_f32_16x16x32_bf16(
                    vf, c1.v, oacc[1][vn], 0, 0, 0);
            }
        }
        __builtin_amdgcn_s_setprio(0);
    }

    // epilogue: O^T layout -> y[b][qrow][h*128 + d], d = vn*16+quad*4+r
#pragma unroll
    for (int p = 0; p < 2; ++p) {
        lsum[p] += __shfl_xor(lsum[p], 16);
        lsum[p] += __shfl_xor(lsum[p], 32);
        const float inv = 1.0f / lsum[p];
        const size_t ybase =
            ((size_t)b * 2048 + qt0 + p * 64 + wq + l16) * 2048 +
            h * 128 + quad * 4;
#pragma unroll
        for (int vn = 0; vn < 8; ++vn) {
            bf16x4 o = {(__bf16)(oacc[p][vn][0] * inv),
                        (__bf16)(oacc[p][vn][1] * inv),
                        (__bf16)(oacc[p][vn][2] * inv),
                        (__bf16)(oacc[p][vn][3] * inv)};
            *(bf16x4*)(y + ybase + vn * 16) = o;
        }
    }
}

// ---------------------------------------------------------------------------
extern "C" void kernel_launch(void* const* d_in, const int* in_sizes, int n_in,
                              void* d_out, int out_size, void* d_ws, size_t ws_size,
                              hipStream_t stream) {
    const float* x     = (const float*)d_in[0];
    const float* Wq    = (const float*)d_in[1];
    const float* Wk    = (const float*)d_in[2];
    const float* Wv    = (const float*)d_in[3];
    const float* Wproj = (const float*)d_in[4];
    const float* qgain = (const float*)d_in[5];
    float* outp = (float*)d_out;

    // workspace layout (bf16 elems)
    __bf16* xb  = (__bf16*)d_ws;          // 16777216
    __bf16* Wqb = xb  + 16777216;         // 4194304
    __bf16* Wkb = Wqb + 4194304;          // 1048576  (Wkb+Wvb = fused [1024][2048])
    __bf16* Wvb = Wkb + 1048576;          // 1048576
    __bf16* Wpb = Wvb + 1048576;          // 4194304
    __bf16* q   = Wpb + 4194304;          // 16777216
    __bf16* kvb = q   + 16777216;         // 8388608  [4*2048][1024]: k|v fused
    __bf16* vt  = kvb + 8388608;          // 4194304  [4][512][2048]
    __bf16* y   = q;                      // alias: blocks read their own q rows
                                          // before writing them; cols disjoint by h

    dim3 blk(256);
    cvt_all<<<dim3(27262976 / 1024), blk, 0, stream>>>(x, Wq, Wk, Wv, Wproj, xb);

    // 256-row tiles; grid = (bm, bn) so XCD = bm%8 (A-panel L2 sharing).
    gemm4buf<4, __bf16><<<dim3(32, 8), dim3(512), 0, stream>>>(xb, Wqb, q, 8192, 2048, 2048);
    gemm4buf<2, __bf16><<<dim3(32, 8), dim3(512), 0, stream>>>(xb, Wkb, kvb, 8192, 1024, 2048);
    k_norm_rope<<<dim3((4 * 2048 * 4) / 4), blk, 0, stream>>>(kvb);
    transpose_v<<<dim3(32, 8, 4), blk, 0, stream>>>(kvb, vt);
    attn<<<dim3(64, 16), blk, 0, stream>>>(q, kvb, vt, y, qgain);
    gemm4buf<4, float><<<dim3(32, 8), dim3(512), 0, stream>>>(y, Wpb, outp, 8192, 2048, 2048);
}